// Round 15
// baseline (187.121 us; speedup 1.0000x reference)
//
#include <hip/hip_runtime.h>
#include <math.h>

#define N_NODES 50000
#define N_EDGES 800000
#define IN_F    256
#define HID_F   128
#define OUT_F   40
#define W0N     (3*HID_F)   // 384
#define W1N     (3*OUT_F)   // 120
#define NB      ((N_NODES + 255) / 256)   // 196

#define SEG     128
#define EPB     (N_EDGES / SEG)           // 6250 edges per segment
#define NWORD   (N_NODES / 2)             // 25000 packed words (2 nodes/word)
#define WB      ((NWORD + 255) / 256)     // 98 scanseg blocks

// k_hp block ranges: [0,SEG) hist | x convert | pack W0 | pack W1
#define XB   ((N_NODES * IN_F) / (256 * 16))   // 3125
#define P0B  ((IN_F * W0N) / 256)              // 384
#define P1B  ((HID_F * W1N) / 256)             // 60
#define HPB0 (SEG)
#define HPB1 (SEG + XB)
#define HPB2 (SEG + XB + P0B)
#define HPREPB (SEG + XB + P0B + P1B)          // 3697

typedef __attribute__((ext_vector_type(8))) unsigned short ushort8;
typedef __attribute__((ext_vector_type(4))) unsigned short ushort4v;
typedef __attribute__((ext_vector_type(8))) __bf16 bf16x8;
typedef __attribute__((ext_vector_type(4))) float f32x4;
typedef __attribute__((ext_vector_type(2))) float f32x2;

static __device__ __forceinline__ float sigmoidf_(float x) {
    return 1.0f / (1.0f + expf(-x));
}

static __device__ __forceinline__ unsigned short f2bf(float f) {
    unsigned u = __float_as_uint(f);
    u += 0x7FFFu + ((u >> 16) & 1u);
    return (unsigned short)(u >> 16);
}

static __device__ __forceinline__ float bflo(unsigned u) { return __uint_as_float(u << 16); }
static __device__ __forceinline__ float bfhi(unsigned u) { return __uint_as_float(u & 0xffff0000u); }
static __device__ __forceinline__ int rfl(int v) { return __builtin_amdgcn_readfirstlane(v); }

// ------- fused: segmented LDS histogram | x->bf16 | pack W0^T | pack W1^T(k-perm) -------

__global__ __launch_bounds__(256) void k_hp(
        const int* __restrict__ ei, unsigned* __restrict__ segHist,
        unsigned short* __restrict__ rank, unsigned* __restrict__ rc,
        const float* __restrict__ x, unsigned short* __restrict__ xb,
        const float* __restrict__ Wl0, const float* __restrict__ Wh0,
        const float* __restrict__ Wm0, unsigned short* __restrict__ W0t,
        const float* __restrict__ Wl1, const float* __restrict__ Wh1,
        const float* __restrict__ Wm1, unsigned short* __restrict__ W1t) {
    __shared__ unsigned hist[NWORD];   // 100 KB (only hist blocks touch it)
    int b = blockIdx.x, t = threadIdx.x;
    if (b < SEG) {
        int seg = b;
        for (int i = t; i < NWORD; i += 256) hist[i] = 0;
        __syncthreads();
        int base = seg * EPB;
        for (int k = t; k < EPB; k += 256) {
            int e = base + k;
            int r = ei[e];
            int c = ei[N_EDGES + e];
            unsigned old = atomicAdd(&hist[r >> 1], (r & 1) ? 0x10000u : 1u);
            unsigned lr = (r & 1) ? (old >> 16) : (old & 0xffffu);
            rank[e] = (unsigned short)lr;
            rc[e] = ((unsigned)r << 16) | (unsigned)c;
        }
        __syncthreads();
        unsigned* dst = segHist + (size_t)seg * NWORD;
        for (int i = t; i < NWORD; i += 256) dst[i] = hist[i];
    } else if (b < HPB1) {
        size_t idx = (size_t)(b - HPB0) * 4096 + t * 16;
        float4 f0 = *(const float4*)(x + idx);
        float4 f1 = *(const float4*)(x + idx + 4);
        float4 f2 = *(const float4*)(x + idx + 8);
        float4 f3 = *(const float4*)(x + idx + 12);
        ushort8 u0, u1;
        u0[0]=f2bf(f0.x); u0[1]=f2bf(f0.y); u0[2]=f2bf(f0.z); u0[3]=f2bf(f0.w);
        u0[4]=f2bf(f1.x); u0[5]=f2bf(f1.y); u0[6]=f2bf(f1.z); u0[7]=f2bf(f1.w);
        u1[0]=f2bf(f2.x); u1[1]=f2bf(f2.y); u1[2]=f2bf(f2.z); u1[3]=f2bf(f2.w);
        u1[4]=f2bf(f3.x); u1[5]=f2bf(f3.y); u1[6]=f2bf(f3.z); u1[7]=f2bf(f3.w);
        *(ushort8*)(xb + idx)     = u0;
        *(ushort8*)(xb + idx + 8) = u1;
    } else if (b < HPB2) {
        int i = (b - HPB1) * 256 + t;
        int n = i / IN_F, k = i % IN_F;
        float v;
        if (n < HID_F)            v = Wl0[k * HID_F + n];
        else if (n < 2 * HID_F)   v = Wh0[k * HID_F + (n - HID_F)];
        else                      v = Wm0[k * HID_F + (n - 2 * HID_F)];
        W0t[i] = f2bf(v);
    } else {
        int i = (b - HPB2) * 256 + t;
        int n = i / HID_F, kp = i % HID_F;
        // k-dim permuted to match hbuf's permuted layout: feat = g*64 + q*16 + c
        int k = ((kp >> 6) << 6) + ((kp & 3) << 4) + ((kp >> 2) & 15);
        float v;
        if (n < OUT_F)            v = Wl1[k * OUT_F + n];
        else if (n < 2 * OUT_F)   v = Wh1[k * OUT_F + (n - OUT_F)];
        else                      v = Wm1[k * OUT_F + (n - 2 * OUT_F)];
        W1t[i] = f2bf(v);
    }
}

// ------- scanseg: in-place segHist -> per-segment offsets; local rowPtr + dinv + blkTot -------

__global__ __launch_bounds__(256) void k_scanseg(
        unsigned* __restrict__ segHist, int* __restrict__ rowPtr,
        float* __restrict__ dinv, int* __restrict__ blkTot) {
    __shared__ int s[256];
    int t = threadIdx.x;
    int w = blockIdx.x * 256 + t;    // packed word = nodes 2w, 2w+1
    int cum0 = 0, cum1 = 0;
    if (w < NWORD) {
        for (int sg = 0; sg < SEG; ++sg) {
            size_t idx = (size_t)sg * NWORD + w;
            unsigned h = segHist[idx];
            segHist[idx] = ((unsigned)cum1 << 16) | (unsigned)cum0;  // offset-before
            cum0 += (int)(h & 0xffffu);
            cum1 += (int)(h >> 16);
        }
    }
    int deg0 = cum0, deg1 = cum1;
    int pair = deg0 + deg1;
    s[t] = pair; __syncthreads();
    for (int d = 1; d < 256; d <<= 1) {
        int x = (t >= d) ? s[t - d] : 0;
        __syncthreads();
        s[t] += x;
        __syncthreads();
    }
    int basep = s[t] - pair;   // exclusive prefix within block
    if (w < NWORD) {
        rowPtr[2 * w]     = basep;
        rowPtr[2 * w + 1] = basep + deg0;
        dinv[2 * w]     = 1.0f / (1.0f + (float)deg0);
        dinv[2 * w + 1] = 1.0f / (1.0f + (float)deg1);
    }
    if (t == 255) blkTot[blockIdx.x] = s[255];
}

__global__ void k_scan2(int* __restrict__ blk) {
    __shared__ int s[256];
    int t = threadIdx.x;
    int v = (t < WB) ? blk[t] : 0;
    s[t] = v; __syncthreads();
    for (int d = 1; d < 256; d <<= 1) {
        int x = (t >= d) ? s[t - d] : 0;
        __syncthreads();
        s[t] += x;
        __syncthreads();
    }
    if (t < WB) blk[t] = s[t] - v;
}

__global__ void k_scan3(const int* __restrict__ blkOff, int* __restrict__ rowPtr) {
    int t = threadIdx.x;
    int gid = blockIdx.x * 256 + t;
    if (gid < N_NODES) rowPtr[gid] += blkOff[gid >> 9];   // 512 nodes per scanseg block
    if (gid == 0) rowPtr[N_NODES] = N_EDGES;
}

// ---------------- bf16 MFMA GEMM (reg double-buffered) + fused CSR-fill ----------------
// tile 128x128, BK=32, 4 waves (2x2).
// EPI=0 (GEMM1): bf16 split write + fp8 byte store to Cq for gn<nsplit.
// EPI=1 (GEMM0): Hs (bf16 perm), Hq (fp8 perm), HmP (bf16 perm).

#define BKP 40   // 32 + 8 pad

template<int EPI>
__global__ __launch_bounds__(256) void k_gemm_fill(
        const unsigned short* __restrict__ A, const unsigned short* __restrict__ Bt,
        unsigned short* __restrict__ C0, int ld0,
        unsigned short* __restrict__ C1, int ld1, int nsplit,
        unsigned char* __restrict__ Cq,
        unsigned short* __restrict__ Hs, unsigned char* __restrict__ Hq,
        unsigned short* __restrict__ HmP,
        int M, int N, int K, int nxt,
        const unsigned* __restrict__ rc, const unsigned short* __restrict__ rank,
        const int* __restrict__ rowPtr, const unsigned short* __restrict__ segOff,
        unsigned short* __restrict__ colIdx) {
    __shared__ unsigned short As[128 * BKP];
    __shared__ unsigned short Bs[128 * BKP];
    int tid  = threadIdx.x;

    if ((int)blockIdx.x >= nxt) {
        int fid = (blockIdx.x - nxt) * gridDim.y + blockIdx.y;
        int e = fid * 256 + tid;
        if (e < N_EDGES) {
            unsigned x = rc[e];
            int r = (int)(x >> 16);
            int seg = e / EPB;
            int pos = rowPtr[r] + (int)segOff[(size_t)seg * N_NODES + r] + (int)rank[e];
            colIdx[pos] = (unsigned short)(x & 0xffffu);
        }
        return;
    }

    int lane = tid & 63, wid = tid >> 6;
    int wr = wid >> 1, wc = wid & 1;
    int bm = blockIdx.y * 128, bn = blockIdx.x * 128;

    int srow = tid >> 1;
    int scol = (tid & 1) * 16;

    int garow = min(bm + srow, M - 1);
    int gbrow = min(bn + srow, N - 1);

    f32x4 acc[4][4];
#pragma unroll
    for (int m = 0; m < 4; ++m)
#pragma unroll
        for (int n = 0; n < 4; ++n)
            acc[m][n] = (f32x4)(0.0f);

    int kg = (lane >> 4) * 8;
    int rA = wr * 64 + (lane & 15);
    int rB = wc * 64 + (lane & 15);

    const unsigned short* srcA = A + (size_t)garow * K + scol;
    const unsigned short* srcB = Bt + (size_t)gbrow * K + scol;
    ushort8 ra0 = *(const ushort8*)(srcA);
    ushort8 ra1 = *(const ushort8*)(srcA + 8);
    ushort8 rb0 = *(const ushort8*)(srcB);
    ushort8 rb1 = *(const ushort8*)(srcB + 8);

    for (int k0 = 0; k0 < K; k0 += 32) {
        *(ushort8*)&As[srow * BKP + scol]     = ra0;
        *(ushort8*)&As[srow * BKP + scol + 8] = ra1;
        *(ushort8*)&Bs[srow * BKP + scol]     = rb0;
        *(ushort8*)&Bs[srow * BKP + scol + 8] = rb1;
        __syncthreads();
        if (k0 + 32 < K) {   // prefetch next K-tile; flies during ds_read+MFMA
            ra0 = *(const ushort8*)(srcA + k0 + 32);
            ra1 = *(const ushort8*)(srcA + k0 + 40);
            rb0 = *(const ushort8*)(srcB + k0 + 32);
            rb1 = *(const ushort8*)(srcB + k0 + 40);
        }

        bf16x8 a[4], b[4];
#pragma unroll
        for (int m = 0; m < 4; ++m)
            a[m] = __builtin_bit_cast(bf16x8, *(const ushort8*)&As[(rA + m * 16) * BKP + kg]);
#pragma unroll
        for (int n = 0; n < 4; ++n)
            b[n] = __builtin_bit_cast(bf16x8, *(const ushort8*)&Bs[(rB + n * 16) * BKP + kg]);
#pragma unroll
        for (int m = 0; m < 4; ++m)
#pragma unroll
            for (int n = 0; n < 4; ++n)
                acc[m][n] = __builtin_amdgcn_mfma_f32_16x16x32_bf16(a[m], b[n], acc[m][n], 0, 0, 0);
        __syncthreads();
    }

    int col  = lane & 15;
    int rsub = (lane >> 4) * 4;

    if (EPI == 0) {
#pragma unroll
        for (int m = 0; m < 4; ++m) {
            int gm0 = bm + wr * 64 + m * 16 + rsub;
#pragma unroll
            for (int n = 0; n < 4; ++n) {
                int gn = bn + wc * 64 + n * 16 + col;
                if (gn >= N) continue;
#pragma unroll
                for (int j = 0; j < 4; ++j) {
                    int gm = gm0 + j;
                    if (gm >= M) continue;
                    float v = acc[m][n][j];
                    unsigned short b = f2bf(v);
                    if (gn < nsplit) {
                        C0[(size_t)gm * ld0 + gn] = b;
                        int pk = __builtin_amdgcn_cvt_pk_fp8_f32(v, v, 0, false);
                        Cq[(size_t)gm * nsplit + gn] = (unsigned char)(pk & 0xff);
                    } else {
                        C1[(size_t)gm * ld1 + (gn - nsplit)] = b;
                    }
                }
            }
        }
    } else {
        // permuted writes; this thread covers pos base = bn + wc*64 + col*4
#pragma unroll
        for (int m = 0; m < 4; ++m) {
            int gm0 = bm + wr * 64 + m * 16 + rsub;
#pragma unroll
            for (int j = 0; j < 4; ++j) {
                int gm = gm0 + j;
                if (gm >= M) continue;
                float v0 = acc[m][0][j], v1 = acc[m][1][j];
                float v2 = acc[m][2][j], v3 = acc[m][3][j];
                ushort4v o;
                o[0] = f2bf(v0); o[1] = f2bf(v1); o[2] = f2bf(v2); o[3] = f2bf(v3);
                if (bn < 256) {
                    int pos = bn + wc * 64 + col * 4;
                    *(ushort4v*)&Hs[(size_t)gm * 256 + pos] = o;
                    int pk = 0;
                    pk = __builtin_amdgcn_cvt_pk_fp8_f32(v0, v1, pk, false);
                    pk = __builtin_amdgcn_cvt_pk_fp8_f32(v2, v3, pk, true);
                    *(unsigned*)&Hq[(size_t)gm * 256 + pos] = (unsigned)pk;
                } else {
                    int pos = wc * 64 + col * 4;
                    *(ushort4v*)&HmP[(size_t)gm * 128 + pos] = o;
                }
            }
        }
    }
}

// ---------------- layer 0: wave-per-node, shfl-decoupled fp8 gather + ACM epilogue ----------------
// (R11-exact version: best measured 50.5 us)
// Hq fp8 perm [256 B/row]; Hs bf16 perm [256]; HmP bf16 perm [128].

__global__ __launch_bounds__(256) void k_layer0(
        const unsigned short* __restrict__ Hs, const unsigned char* __restrict__ Hq,
        const unsigned short* __restrict__ HmP,
        const int* __restrict__ rowPtr, const unsigned short* __restrict__ colIdx,
        const float* __restrict__ dinv,
        const float* __restrict__ al, const float* __restrict__ ah,
        const float* __restrict__ am, const float* __restrict__ att,
        unsigned short* __restrict__ hout) {
    int lane = threadIdx.x & 63;
    int i = blockIdx.x * 4 + (threadIdx.x >> 6);

    int p0 = rfl(rowPtr[i]);
    int p1 = rfl(rowPtr[i + 1]);
    int deg = p1 - p0;
    float a0 = 0.f, a1 = 0.f, a2 = 0.f, a3 = 0.f;
    int off4 = lane * 4;

    auto gath = [&](int js) -> unsigned {
        return *(const unsigned*)(Hq + ((size_t)(unsigned)js << 8) + off4);
    };
    auto addw = [&](unsigned w) {
        f32x2 d0 = __builtin_amdgcn_cvt_pk_f32_fp8((int)w, false);
        f32x2 d1 = __builtin_amdgcn_cvt_pk_f32_fp8((int)w, true);
        a0 += d0.x; a1 += d0.y; a2 += d1.x; a3 += d1.y;
    };

    for (int c = 0; c < deg; c += 64) {
        int rem = deg - c; if (rem > 64) rem = 64;
        int mycol = (int)colIdx[p0 + c + (lane < rem ? lane : 0)];
        int q = 0;
        for (; q + 7 < rem; q += 8) {
            int j0 = rfl(__shfl(mycol, q + 0));
            int j1 = rfl(__shfl(mycol, q + 1));
            int j2 = rfl(__shfl(mycol, q + 2));
            int j3 = rfl(__shfl(mycol, q + 3));
            int j4 = rfl(__shfl(mycol, q + 4));
            int j5 = rfl(__shfl(mycol, q + 5));
            int j6 = rfl(__shfl(mycol, q + 6));
            int j7 = rfl(__shfl(mycol, q + 7));
            unsigned w0 = gath(j0), w1 = gath(j1), w2 = gath(j2), w3 = gath(j3);
            unsigned w4 = gath(j4), w5 = gath(j5), w6 = gath(j6), w7 = gath(j7);
            addw(w0); addw(w1); addw(w2); addw(w3);
            addw(w4); addw(w5); addw(w6); addw(w7);
        }
        for (; q < rem; ++q) {
            int j = rfl(__shfl(mycol, q));
            addw(gath(j));
        }
    }

    uint2 sv = *(const uint2*)(Hs + (size_t)i * 256 + off4);   // 4 bf16 self vals
    float s0 = bflo(sv.x), s1 = bfhi(sv.x), s2 = bflo(sv.y), s3 = bfhi(sv.y);
    float di = dinv[i];
    float l0 = di * (s0 + a0), l1 = di * (s1 + a1);
    float l2 = di * (s2 + a2), l3 = di * (s3 + a3);

    float ol0 = fmaxf(l0, 0.f), ol1 = fmaxf(l1, 0.f);
    float ol2 = fmaxf(l2, 0.f), ol3 = fmaxf(l3, 0.f);
    float oh0 = fmaxf(s0 - l0, 0.f), oh1 = fmaxf(s1 - l1, 0.f);
    float oh2 = fmaxf(s2 - l2, 0.f), oh3 = fmaxf(s3 - l3, 0.f);

    int c0 = ((lane >> 4) << 6) + (lane & 15);   // true feat of q=0

    float om0 = 0.f, om1 = 0.f, om2 = 0.f, om3 = 0.f;
    float prA, prM = 0.f;
    if (lane < 32) {
        uint2 hv = *(const uint2*)(HmP + (size_t)i * 128 + off4);
        om0 = fmaxf(bflo(hv.x), 0.f); om1 = fmaxf(bfhi(hv.x), 0.f);
        om2 = fmaxf(bflo(hv.y), 0.f); om3 = fmaxf(bfhi(hv.y), 0.f);
        prA = ol0 * al[c0] + ol1 * al[c0 + 16] + ol2 * al[c0 + 32] + ol3 * al[c0 + 48];
        prM = om0 * am[c0] + om1 * am[c0 + 16] + om2 * am[c0 + 32] + om3 * am[c0 + 48];
    } else {
        int ch = c0 - 128;
        prA = oh0 * ah[ch] + oh1 * ah[ch + 16] + oh2 * ah[ch + 32] + oh3 * ah[ch + 48];
    }

#pragma unroll
    for (int d = 1; d < 32; d <<= 1) prA += __shfl_xor(prA, d);
#pragma unroll
    for (int d = 1; d < 32; d <<= 1) prM += __shfl_xor(prM, d);
    float g0 = __shfl(prA, 0);
    float g1 = __shfl(prA, 32);
    float g2 = __shfl(prM, 0);

    float sg0 = sigmoidf_(g0), sg1 = sigmoidf_(g1), sg2 = sigmoidf_(g2);
    const float inv3 = (1.0f / 3.0f);
    float e0 = (sg0 * att[0] + sg1 * att[3] + sg2 * att[6]) * inv3;
    float e1 = (sg0 * att[1] + sg1 * att[4] + sg2 * att[7]) * inv3;
    float e2 = (sg0 * att[2] + sg1 * att[5] + sg2 * att[8]) * inv3;
    float mx = fmaxf(e0, fmaxf(e1, e2));
    float x0 = expf(e0 - mx), x1 = expf(e1 - mx), x2 = expf(e2 - mx);
    float inv = 1.0f / (x0 + x1 + x2);
    float c0f = 3.0f * inv * x0, c1f = 3.0f * inv * x1, c2f = 3.0f * inv * x2;

    int src = lane | 32;
    float th0 = __shfl(oh0, src), th1 = __shfl(oh1, src);
    float th2 = __shfl(oh2, src), th3 = __shfl(oh3, src);

    if (lane < 32) {
        // hbuf permuted: pos p = lane*4+q -> true feat c_q (matches W1t k-perm)
        ushort4v o;
        o[0] = f2bf(c0f * ol0 + c1f * th0 + c2f * om0);
        o[1] = f2bf(c0f * ol1 + c1f * th1 + c2f * om1);
        o[2] = f2bf(c0f * ol2 + c1f * th2 + c2f * om2);
        o[3] = f2bf(c0f * ol3 + c1f * th3 + c2f * om3);
        *(ushort4v*)&hout[(size_t)i * 128 + off4] = o;
    }
}

// ---------------- layer 1: wave-per-node, shfl-decoupled fp8 gather + ACM epilogue ----------------
// H1q fp8 plain [80 B/row]; H1g bf16 plain [80] (self); H1m bf16 [40].

__global__ __launch_bounds__(256) void k_layer1(
        const unsigned short* __restrict__ H1g, const unsigned char* __restrict__ H1q,
        const unsigned short* __restrict__ H1m,
        const int* __restrict__ rowPtr, const unsigned short* __restrict__ colIdx,
        const float* __restrict__ dinv,
        const float* __restrict__ al, const float* __restrict__ ah,
        const float* __restrict__ am, const float* __restrict__ att,
        float* __restrict__ out) {
    int lane = threadIdx.x & 63;
    int i = blockIdx.x * 4 + (threadIdx.x >> 6);

    int p0 = rfl(rowPtr[i]);
    int p1 = rfl(rowPtr[i + 1]);
    int deg = p1 - p0;
    float a0 = 0.f, a1 = 0.f, a2 = 0.f, a3 = 0.f;
    bool active = lane < 20;
    int off4 = lane * 4;
    int offc = active ? off4 : 0;    // clamp: inactive lanes load safely in-row

    auto gath = [&](int js) -> unsigned {
        return *(const unsigned*)(H1q + (size_t)((unsigned)js * 80u) + offc);
    };
    auto addw = [&](unsigned w) {
        f32x2 d0 = __builtin_amdgcn_cvt_pk_f32_fp8((int)w, false);
        f32x2 d1 = __builtin_amdgcn_cvt_pk_f32_fp8((int)w, true);
        a0 += d0.x; a1 += d0.y; a2 += d1.x; a3 += d1.y;
    };

    for (int c = 0; c < deg; c += 64) {
        int rem = deg - c; if (rem > 64) rem = 64;
        int mycol = (int)colIdx[p0 + c + (lane < rem ? lane : 0)];
        int q = 0;
        for (; q + 7 < rem; q += 8) {
            int j0 = rfl(__shfl(mycol, q + 0));
            int j1 = rfl(__shfl(mycol, q + 1));
            int j2 = rfl(__shfl(mycol, q + 2));
            int j3 = rfl(__shfl(mycol, q + 3));
            int j4 = rfl(__shfl(mycol, q + 4));
            int j5 = rfl(__shfl(mycol, q + 5));
            int j6 = rfl(__shfl(mycol, q + 6));
            int j7 = rfl(__shfl(mycol, q + 7));
            unsigned w0 = gath(j0), w1 = gath(j1), w2 = gath(j2), w3 = gath(j3);
            unsigned w4 = gath(j4), w5 = gath(j5), w6 = gath(j6), w7 = gath(j7);
            addw(w0); addw(w1); addw(w2); addw(w3);
            addw(w4); addw(w5); addw(w6); addw(w7);
        }
        for (; q < rem; ++q) {
            int j = rfl(__shfl(mycol, q));
            addw(gath(j));
        }
    }

    float s0 = 0.f, s1 = 0.f, s2 = 0.f, s3 = 0.f;
    if (active) {
        uint2 sv = *(const uint2*)(H1g + (size_t)i * 80 + off4);  // 4 bf16 self
        s0 = bflo(sv.x); s1 = bfhi(sv.x); s2 = bflo(sv.y); s3 = bfhi(sv.y);
    }
    float di = dinv[i];
    float l0 = di * (s0 + a0), l1 = di * (s1 + a1);
    float l2 = di * (s2 + a2), l3 = di * (s3 + a3);

    float ol0 = fmaxf(l0, 0.f), ol1 = fmaxf(l1, 0.f);
    float ol2 = fmaxf(l2, 0.f), ol3 = fmaxf(l3, 0.f);
    float oh0 = fmaxf(s0 - l0, 0.f), oh1 = fmaxf(s1 - l1, 0.f);
    float oh2 = fmaxf(s2 - l2, 0.f), oh3 = fmaxf(s3 - l3, 0.f);

    float om0 = 0.f, om1 = 0.f, om2 = 0.f, om3 = 0.f;
    float r0 = 0.f, r1 = 0.f, r2 = 0.f;
    if (lane < 10) {
        uint2 hv = *(const uint2*)(H1m + (size_t)i * 40 + off4);
        om0 = fmaxf(bflo(hv.x), 0.f); om1 = fmaxf(bfhi(hv.x), 0.f);
        om2 = fmaxf(bflo(hv.y), 0.f); om3 = fmaxf(bfhi(hv.y), 0.f);
        float4 alv = *(const float4*)(al + off4);
        float4 amv = *(const float4*)(am + off4);
        r0 = ol0 * alv.x + ol1 * alv.y + ol2 * alv.z + ol3 * alv.w;
        r2 = om0 * amv.x + om1 * amv.y + om2 * amv.z + om3 * amv.w;
    } else if (lane < 20) {
        float4 ahv = *(const float4*)(ah + (off4 - 40));
        r1 = oh0 * ahv.x + oh1 * ahv.y + oh2 * ahv.z + oh3 * ahv.w;
    }

#pragma unroll
    for (int d = 1; d < 64; d <<= 1) r0 += __shfl_xor(r0, d);
#pragma unroll
    for (int d = 1; d < 64; d <<= 1) r1 += __shfl_xor(r1, d);
#pragma unroll
    for (int d = 1; d < 64; d <<= 1) r2 += __shfl_xor(r2, d);

    float sg0 = sigmoidf_(r0), sg1 = sigmoidf_(r1), sg2 = sigmoidf_(r2);
    const float inv3 = (1.0f / 3.0f);
    float e0 = (sg0 * att[0] + sg1 * att[3] + sg2 * att[6]) * inv3;
    float e1 = (sg0 * att[1] + sg1 * att[4] + sg2 * att[7]) * inv3;
    float e2 = (sg0 * att[2] + sg1 * att[5] + sg2 * att[8]) * inv3;
    float mx = fmaxf(e0, fmaxf(e1, e2));
    float x0 = expf(e0 - mx), x1 = expf(e1 - mx), x2 = expf(e2 - mx);
    float inv = 1.0f / (x0 + x1 + x2);
    float c0 = 3.0f * inv * x0, c1 = 3.0f * inv * x1, c2 = 3.0f * inv * x2;

    // oh for output feat f (=4l+k) lives on lane l+10, same k
    int src = (lane + 10) & 63;
    float th0 = __shfl(oh0, src), th1 = __shfl(oh1, src);
    float th2 = __shfl(oh2, src), th3 = __shfl(oh3, src);

    if (lane < 10) {
        float4 o;
        o.x = c0 * ol0 + c1 * th0 + c2 * om0;
        o.y = c0 * ol1 + c1 * th1 + c2 * om1;
        o.z = c0 * ol2 + c1 * th2 + c2 * om2;
        o.w = c0 * ol3 + c1 * th3 + c2 * om3;
        *(float4*)&out[(size_t)i * 40 + off4] = o;
    }
}

// ---------------- launch ----------------

extern "C" void kernel_launch(void* const* d_in, const int* in_sizes, int n_in,
                              void* d_out, int out_size, void* d_ws, size_t ws_size,
                              hipStream_t stream) {
    const float* x    = (const float*)d_in[0];
    const int*   ei   = (const int*)d_in[1];
    const float* Wl0  = (const float*)d_in[2];
    const float* Wh0  = (const float*)d_in[3];
    const float* Wm0  = (const float*)d_in[4];
    const float* al0  = (const float*)d_in[5];
    const float* ah0  = (const float*)d_in[6];
    const float* am0  = (const float*)d_in[7];
    const float* att0 = (const float*)d_in[8];
    const float* Wl1  = (const float*)d_in[9];
    const float* Wh1  = (const float*)d_in[10];
    const float* Wm1  = (const float*)d_in[11];
    const float* al1  = (const float*)d_in[12];
    const float* ah1  = (const float*)d_in[13];
    const float* am1  = (const float*)d_in[14];
    const float* att1 = (const float*)d_in[15];
    float* out = (float*)d_out;

    char* ws = (char*)d_ws;
    size_t off = 0;
    auto alloc = [&](size_t bytes) -> char* {
        char* p = ws + off;
        off += (bytes + 255) & ~(size_t)255;
        return p;
    };
    int*      rowPtr  = (int*)     alloc((size_t)(N_NODES + 1) * 4);
    int*      blkTot  = (int*)     alloc(256 * 4);
    unsigned* segHist = (unsigned*)alloc((size_t)SEG * NWORD * 4);   // 12.8 MB
    unsigned short* rank   = (unsigned short*)alloc((size_t)N_EDGES * 2);
    unsigned*       rc     = (unsigned*)      alloc((size_t)N_EDGES * 4);
    unsigned short* colIdx = (unsigned short*)alloc((size_t)N_EDGES * 2 + 256);
    float* dinv   = (float*)alloc((size_t)N_NODES * 4);
    unsigned short* W0t  = (unsigned short*)alloc((size_t)W0N * IN_F * 2);
    unsigned short* W1t  = (unsigned short*)alloc((size_t)W1N * HID_F * 2);
    unsigned short* xb   = (unsigned short*)alloc((size_t)N_NODES * IN_F * 2);
    unsigned short* Hs   = (unsigned short*)alloc((size_t)N_NODES * 256 * 2);
    unsigned char*  Hq   = (unsigned char*) alloc((size_t)N_NODES * 256);
    unsigned short* HmP  = (unsigned short*)alloc((size_t)N_NODES * 128 * 2);
    unsigned short* H1g  = (unsigned short*)alloc((size_t)N_NODES * 80 * 2);
    unsigned char*  H1q  = (unsigned char*) alloc((size_t)N_NODES * 80 + 256);  // +pad
    unsigned short* H1m  = (unsigned short*)alloc((size_t)N_NODES * 40 * 2);
    unsigned short* hbuf = (unsigned short*)alloc((size_t)N_NODES * HID_F * 2);

    // 1. fused: segmented LDS histogram | x->bf16 | W packs
    k_hp<<<HPREPB, 256, 0, stream>>>(ei, segHist, rank, rc,
                                     x, xb, Wl0, Wh0, Wm0, W0t,
                                     Wl1, Wh1, Wm1, W1t);
    // 2. segment-offset scan + local rowPtr + dinv
    k_scanseg<<<WB, 256, 0, stream>>>(segHist, rowPtr, dinv, blkTot);
    // 3-4. block-offset scan + apply
    k_scan2<<<1, 256, 0, stream>>>(blkTot);
    k_scan3<<<NB, 256, 0, stream>>>(blkTot, rowPtr);
    // 5. GEMM0 (layer-0 epilogue: Hs/Hq/HmP) with fused atomic-free CSR fill
    {
        dim3 grid(3 + 8, (N_NODES + 127) / 128);
        k_gemm_fill<1><<<grid, 256, 0, stream>>>(xb, W0t,
                                                 nullptr, 0, nullptr, 0, 0, nullptr,
                                                 Hs, Hq, HmP,
                                                 N_NODES, W0N, IN_F, 3,
                                                 rc, rank, rowPtr,
                                                 (const unsigned short*)segHist, colIdx);
    }
    // 6. layer-0 aggregate + epilogue (1 wave per node, R11-exact)
    k_layer0<<<N_NODES / 4, 256, 0, stream>>>(Hs, Hq, HmP, rowPtr, colIdx, dinv,
                                              al0, ah0, am0, att0, hbuf);
    // 7. GEMM1 (bf16 H1g/H1m + fp8 H1q)
    {
        dim3 grid(1, (N_NODES + 127) / 128);
        k_gemm_fill<0><<<grid, 256, 0, stream>>>(hbuf, W1t,
                                                 H1g, 80, H1m, 40, 80, H1q,
                                                 nullptr, nullptr, nullptr,
                                                 N_NODES, W1N, HID_F, 1,
                                                 nullptr, nullptr, nullptr, nullptr, nullptr);
    }
    // 8. layer-1 aggregate + epilogue
    k_layer1<<<N_NODES / 4, 256, 0, stream>>>(H1g, H1q, H1m, rowPtr, colIdx, dinv,
                                              al1, ah1, am1, att1, out);
}

// Round 16
// 186.730 us; speedup vs baseline: 1.0021x; 1.0021x over previous
//
#include <hip/hip_runtime.h>
#include <math.h>

#define N_NODES 50000
#define N_EDGES 800000
#define IN_F    256
#define HID_F   128
#define OUT_F   40
#define W0N     (3*HID_F)   // 384
#define W1N     (3*OUT_F)   // 120
#define NB      ((N_NODES + 255) / 256)   // 196

#define SEG     128
#define EPB     (N_EDGES / SEG)           // 6250 edges per segment
#define NWORD   (N_NODES / 2)             // 25000 packed words (2 nodes/word)
#define WB      ((NWORD + 255) / 256)     // 98 scanseg blocks

// k_hp block ranges: [0,SEG) hist | x convert | pack W0 | pack W1
#define XB   ((N_NODES * IN_F) / (256 * 16))   // 3125
#define P0B  ((IN_F * W0N) / 256)              // 384
#define P1B  ((HID_F * W1N) / 256)             // 60
#define HPB0 (SEG)
#define HPB1 (SEG + XB)
#define HPB2 (SEG + XB + P0B)
#define HPREPB (SEG + XB + P0B + P1B)          // 3697

typedef __attribute__((ext_vector_type(8))) unsigned short ushort8;
typedef __attribute__((ext_vector_type(4))) unsigned short ushort4v;
typedef __attribute__((ext_vector_type(8))) __bf16 bf16x8;
typedef __attribute__((ext_vector_type(4))) float f32x4;
typedef __attribute__((ext_vector_type(2))) float f32x2;

static __device__ __forceinline__ float sigmoidf_(float x) {
    return 1.0f / (1.0f + expf(-x));
}

static __device__ __forceinline__ unsigned short f2bf(float f) {
    unsigned u = __float_as_uint(f);
    u += 0x7FFFu + ((u >> 16) & 1u);
    return (unsigned short)(u >> 16);
}

static __device__ __forceinline__ float bflo(unsigned u) { return __uint_as_float(u << 16); }
static __device__ __forceinline__ float bfhi(unsigned u) { return __uint_as_float(u & 0xffff0000u); }
static __device__ __forceinline__ int rfl(int v) { return __builtin_amdgcn_readfirstlane(v); }

// ------- fused: segmented LDS histogram | x->bf16 | pack W0^T | pack W1^T(k-perm) -------

__global__ __launch_bounds__(256) void k_hp(
        const int* __restrict__ ei, unsigned* __restrict__ segHist,
        unsigned short* __restrict__ rank, unsigned* __restrict__ rc,
        const float* __restrict__ x, unsigned short* __restrict__ xb,
        const float* __restrict__ Wl0, const float* __restrict__ Wh0,
        const float* __restrict__ Wm0, unsigned short* __restrict__ W0t,
        const float* __restrict__ Wl1, const float* __restrict__ Wh1,
        const float* __restrict__ Wm1, unsigned short* __restrict__ W1t) {
    __shared__ unsigned hist[NWORD];   // 100 KB (only hist blocks touch it)
    int b = blockIdx.x, t = threadIdx.x;
    if (b < SEG) {
        int seg = b;
        for (int i = t; i < NWORD; i += 256) hist[i] = 0;
        __syncthreads();
        int base = seg * EPB;
        for (int k = t; k < EPB; k += 256) {
            int e = base + k;
            int r = ei[e];
            int c = ei[N_EDGES + e];
            unsigned old = atomicAdd(&hist[r >> 1], (r & 1) ? 0x10000u : 1u);
            unsigned lr = (r & 1) ? (old >> 16) : (old & 0xffffu);
            rank[e] = (unsigned short)lr;
            rc[e] = ((unsigned)r << 16) | (unsigned)c;
        }
        __syncthreads();
        unsigned* dst = segHist + (size_t)seg * NWORD;
        for (int i = t; i < NWORD; i += 256) dst[i] = hist[i];
    } else if (b < HPB1) {
        size_t idx = (size_t)(b - HPB0) * 4096 + t * 16;
        float4 f0 = *(const float4*)(x + idx);
        float4 f1 = *(const float4*)(x + idx + 4);
        float4 f2 = *(const float4*)(x + idx + 8);
        float4 f3 = *(const float4*)(x + idx + 12);
        ushort8 u0, u1;
        u0[0]=f2bf(f0.x); u0[1]=f2bf(f0.y); u0[2]=f2bf(f0.z); u0[3]=f2bf(f0.w);
        u0[4]=f2bf(f1.x); u0[5]=f2bf(f1.y); u0[6]=f2bf(f1.z); u0[7]=f2bf(f1.w);
        u1[0]=f2bf(f2.x); u1[1]=f2bf(f2.y); u1[2]=f2bf(f2.z); u1[3]=f2bf(f2.w);
        u1[4]=f2bf(f3.x); u1[5]=f2bf(f3.y); u1[6]=f2bf(f3.z); u1[7]=f2bf(f3.w);
        *(ushort8*)(xb + idx)     = u0;
        *(ushort8*)(xb + idx + 8) = u1;
    } else if (b < HPB2) {
        int i = (b - HPB1) * 256 + t;
        int n = i / IN_F, k = i % IN_F;
        float v;
        if (n < HID_F)            v = Wl0[k * HID_F + n];
        else if (n < 2 * HID_F)   v = Wh0[k * HID_F + (n - HID_F)];
        else                      v = Wm0[k * HID_F + (n - 2 * HID_F)];
        W0t[i] = f2bf(v);
    } else {
        int i = (b - HPB2) * 256 + t;
        int n = i / HID_F, kp = i % HID_F;
        // k-dim permuted to match hbuf's permuted layout: feat = g*64 + q*16 + c
        int k = ((kp >> 6) << 6) + ((kp & 3) << 4) + ((kp >> 2) & 15);
        float v;
        if (n < OUT_F)            v = Wl1[k * OUT_F + n];
        else if (n < 2 * OUT_F)   v = Wh1[k * OUT_F + (n - OUT_F)];
        else                      v = Wm1[k * OUT_F + (n - 2 * OUT_F)];
        W1t[i] = f2bf(v);
    }
}

// ------- scanseg: in-place segHist -> per-segment offsets; local rowPtr + dinv + blkTot -------

__global__ __launch_bounds__(256) void k_scanseg(
        unsigned* __restrict__ segHist, int* __restrict__ rowPtr,
        float* __restrict__ dinv, int* __restrict__ blkTot) {
    __shared__ int s[256];
    int t = threadIdx.x;
    int w = blockIdx.x * 256 + t;    // packed word = nodes 2w, 2w+1
    int cum0 = 0, cum1 = 0;
    if (w < NWORD) {
        for (int sg = 0; sg < SEG; ++sg) {
            size_t idx = (size_t)sg * NWORD + w;
            unsigned h = segHist[idx];
            segHist[idx] = ((unsigned)cum1 << 16) | (unsigned)cum0;  // offset-before
            cum0 += (int)(h & 0xffffu);
            cum1 += (int)(h >> 16);
        }
    }
    int deg0 = cum0, deg1 = cum1;
    int pair = deg0 + deg1;
    s[t] = pair; __syncthreads();
    for (int d = 1; d < 256; d <<= 1) {
        int x = (t >= d) ? s[t - d] : 0;
        __syncthreads();
        s[t] += x;
        __syncthreads();
    }
    int basep = s[t] - pair;   // exclusive prefix within block
    if (w < NWORD) {
        rowPtr[2 * w]     = basep;
        rowPtr[2 * w + 1] = basep + deg0;
        dinv[2 * w]     = 1.0f / (1.0f + (float)deg0);
        dinv[2 * w + 1] = 1.0f / (1.0f + (float)deg1);
    }
    if (t == 255) blkTot[blockIdx.x] = s[255];
}

__global__ void k_scan2(int* __restrict__ blk) {
    __shared__ int s[256];
    int t = threadIdx.x;
    int v = (t < WB) ? blk[t] : 0;
    s[t] = v; __syncthreads();
    for (int d = 1; d < 256; d <<= 1) {
        int x = (t >= d) ? s[t - d] : 0;
        __syncthreads();
        s[t] += x;
        __syncthreads();
    }
    if (t < WB) blk[t] = s[t] - v;
}

__global__ void k_scan3(const int* __restrict__ blkOff, int* __restrict__ rowPtr) {
    int t = threadIdx.x;
    int gid = blockIdx.x * 256 + t;
    if (gid < N_NODES) rowPtr[gid] += blkOff[gid >> 9];   // 512 nodes per scanseg block
    if (gid == 0) rowPtr[N_NODES] = N_EDGES;
}

// ---------------- bf16 MFMA GEMM (reg double-buffered) + fused CSR-fill ----------------
// tile 128x128, BK=32, 4 waves (2x2).
// EPI=0 (GEMM1): bf16 split write + fp8 byte store to Cq for gn<nsplit.
// EPI=1 (GEMM0): Hs (bf16 perm), Hq (fp8 perm), HmP (bf16 perm).

#define BKP 40   // 32 + 8 pad

template<int EPI>
__global__ __launch_bounds__(256) void k_gemm_fill(
        const unsigned short* __restrict__ A, const unsigned short* __restrict__ Bt,
        unsigned short* __restrict__ C0, int ld0,
        unsigned short* __restrict__ C1, int ld1, int nsplit,
        unsigned char* __restrict__ Cq,
        unsigned short* __restrict__ Hs, unsigned char* __restrict__ Hq,
        unsigned short* __restrict__ HmP,
        int M, int N, int K, int nxt,
        const unsigned* __restrict__ rc, const unsigned short* __restrict__ rank,
        const int* __restrict__ rowPtr, const unsigned short* __restrict__ segOff,
        unsigned short* __restrict__ colIdx) {
    __shared__ unsigned short As[128 * BKP];
    __shared__ unsigned short Bs[128 * BKP];
    int tid  = threadIdx.x;

    if ((int)blockIdx.x >= nxt) {
        int fid = (blockIdx.x - nxt) * gridDim.y + blockIdx.y;
        int e = fid * 256 + tid;
        if (e < N_EDGES) {
            unsigned x = rc[e];
            int r = (int)(x >> 16);
            int seg = e / EPB;
            int pos = rowPtr[r] + (int)segOff[(size_t)seg * N_NODES + r] + (int)rank[e];
            colIdx[pos] = (unsigned short)(x & 0xffffu);
        }
        return;
    }

    int lane = tid & 63, wid = tid >> 6;
    int wr = wid >> 1, wc = wid & 1;
    int bm = blockIdx.y * 128, bn = blockIdx.x * 128;

    int srow = tid >> 1;
    int scol = (tid & 1) * 16;

    int garow = min(bm + srow, M - 1);
    int gbrow = min(bn + srow, N - 1);

    f32x4 acc[4][4];
#pragma unroll
    for (int m = 0; m < 4; ++m)
#pragma unroll
        for (int n = 0; n < 4; ++n)
            acc[m][n] = (f32x4)(0.0f);

    int kg = (lane >> 4) * 8;
    int rA = wr * 64 + (lane & 15);
    int rB = wc * 64 + (lane & 15);

    const unsigned short* srcA = A + (size_t)garow * K + scol;
    const unsigned short* srcB = Bt + (size_t)gbrow * K + scol;
    ushort8 ra0 = *(const ushort8*)(srcA);
    ushort8 ra1 = *(const ushort8*)(srcA + 8);
    ushort8 rb0 = *(const ushort8*)(srcB);
    ushort8 rb1 = *(const ushort8*)(srcB + 8);

    for (int k0 = 0; k0 < K; k0 += 32) {
        *(ushort8*)&As[srow * BKP + scol]     = ra0;
        *(ushort8*)&As[srow * BKP + scol + 8] = ra1;
        *(ushort8*)&Bs[srow * BKP + scol]     = rb0;
        *(ushort8*)&Bs[srow * BKP + scol + 8] = rb1;
        __syncthreads();
        if (k0 + 32 < K) {   // prefetch next K-tile; flies during ds_read+MFMA
            ra0 = *(const ushort8*)(srcA + k0 + 32);
            ra1 = *(const ushort8*)(srcA + k0 + 40);
            rb0 = *(const ushort8*)(srcB + k0 + 32);
            rb1 = *(const ushort8*)(srcB + k0 + 40);
        }

        bf16x8 a[4], b[4];
#pragma unroll
        for (int m = 0; m < 4; ++m)
            a[m] = __builtin_bit_cast(bf16x8, *(const ushort8*)&As[(rA + m * 16) * BKP + kg]);
#pragma unroll
        for (int n = 0; n < 4; ++n)
            b[n] = __builtin_bit_cast(bf16x8, *(const ushort8*)&Bs[(rB + n * 16) * BKP + kg]);
#pragma unroll
        for (int m = 0; m < 4; ++m)
#pragma unroll
            for (int n = 0; n < 4; ++n)
                acc[m][n] = __builtin_amdgcn_mfma_f32_16x16x32_bf16(a[m], b[n], acc[m][n], 0, 0, 0);
        __syncthreads();
    }

    int col  = lane & 15;
    int rsub = (lane >> 4) * 4;

    if (EPI == 0) {
#pragma unroll
        for (int m = 0; m < 4; ++m) {
            int gm0 = bm + wr * 64 + m * 16 + rsub;
#pragma unroll
            for (int n = 0; n < 4; ++n) {
                int gn = bn + wc * 64 + n * 16 + col;
                if (gn >= N) continue;
#pragma unroll
                for (int j = 0; j < 4; ++j) {
                    int gm = gm0 + j;
                    if (gm >= M) continue;
                    float v = acc[m][n][j];
                    unsigned short b = f2bf(v);
                    if (gn < nsplit) {
                        C0[(size_t)gm * ld0 + gn] = b;
                        int pk = __builtin_amdgcn_cvt_pk_fp8_f32(v, v, 0, false);
                        Cq[(size_t)gm * nsplit + gn] = (unsigned char)(pk & 0xff);
                    } else {
                        C1[(size_t)gm * ld1 + (gn - nsplit)] = b;
                    }
                }
            }
        }
    } else {
        // permuted writes; this thread covers pos base = bn + wc*64 + col*4
#pragma unroll
        for (int m = 0; m < 4; ++m) {
            int gm0 = bm + wr * 64 + m * 16 + rsub;
#pragma unroll
            for (int j = 0; j < 4; ++j) {
                int gm = gm0 + j;
                if (gm >= M) continue;
                float v0 = acc[m][0][j], v1 = acc[m][1][j];
                float v2 = acc[m][2][j], v3 = acc[m][3][j];
                ushort4v o;
                o[0] = f2bf(v0); o[1] = f2bf(v1); o[2] = f2bf(v2); o[3] = f2bf(v3);
                if (bn < 256) {
                    int pos = bn + wc * 64 + col * 4;
                    *(ushort4v*)&Hs[(size_t)gm * 256 + pos] = o;
                    int pk = 0;
                    pk = __builtin_amdgcn_cvt_pk_fp8_f32(v0, v1, pk, false);
                    pk = __builtin_amdgcn_cvt_pk_fp8_f32(v2, v3, pk, true);
                    *(unsigned*)&Hq[(size_t)gm * 256 + pos] = (unsigned)pk;
                } else {
                    int pos = wc * 64 + col * 4;
                    *(ushort4v*)&HmP[(size_t)gm * 128 + pos] = o;
                }
            }
        }
    }
}

// ---------------- layer 0: wave-per-node, shfl-decoupled fp8 gather + ACM epilogue ----------------
// (R11-exact version: best measured 50.5 us)
// Hq fp8 perm [256 B/row]; Hs bf16 perm [256]; HmP bf16 perm [128].

__global__ __launch_bounds__(256) void k_layer0(
        const unsigned short* __restrict__ Hs, const unsigned char* __restrict__ Hq,
        const unsigned short* __restrict__ HmP,
        const int* __restrict__ rowPtr, const unsigned short* __restrict__ colIdx,
        const float* __restrict__ dinv,
        const float* __restrict__ al, const float* __restrict__ ah,
        const float* __restrict__ am, const float* __restrict__ att,
        unsigned short* __restrict__ hout) {
    int lane = threadIdx.x & 63;
    int i = blockIdx.x * 4 + (threadIdx.x >> 6);

    int p0 = rfl(rowPtr[i]);
    int p1 = rfl(rowPtr[i + 1]);
    int deg = p1 - p0;
    float a0 = 0.f, a1 = 0.f, a2 = 0.f, a3 = 0.f;
    int off4 = lane * 4;

    auto gath = [&](int js) -> unsigned {
        return *(const unsigned*)(Hq + ((size_t)(unsigned)js << 8) + off4);
    };
    auto addw = [&](unsigned w) {
        f32x2 d0 = __builtin_amdgcn_cvt_pk_f32_fp8((int)w, false);
        f32x2 d1 = __builtin_amdgcn_cvt_pk_f32_fp8((int)w, true);
        a0 += d0.x; a1 += d0.y; a2 += d1.x; a3 += d1.y;
    };

    for (int c = 0; c < deg; c += 64) {
        int rem = deg - c; if (rem > 64) rem = 64;
        int mycol = (int)colIdx[p0 + c + (lane < rem ? lane : 0)];
        int q = 0;
        for (; q + 7 < rem; q += 8) {
            int j0 = rfl(__shfl(mycol, q + 0));
            int j1 = rfl(__shfl(mycol, q + 1));
            int j2 = rfl(__shfl(mycol, q + 2));
            int j3 = rfl(__shfl(mycol, q + 3));
            int j4 = rfl(__shfl(mycol, q + 4));
            int j5 = rfl(__shfl(mycol, q + 5));
            int j6 = rfl(__shfl(mycol, q + 6));
            int j7 = rfl(__shfl(mycol, q + 7));
            unsigned w0 = gath(j0), w1 = gath(j1), w2 = gath(j2), w3 = gath(j3);
            unsigned w4 = gath(j4), w5 = gath(j5), w6 = gath(j6), w7 = gath(j7);
            addw(w0); addw(w1); addw(w2); addw(w3);
            addw(w4); addw(w5); addw(w6); addw(w7);
        }
        for (; q < rem; ++q) {
            int j = rfl(__shfl(mycol, q));
            addw(gath(j));
        }
    }

    uint2 sv = *(const uint2*)(Hs + (size_t)i * 256 + off4);   // 4 bf16 self vals
    float s0 = bflo(sv.x), s1 = bfhi(sv.x), s2 = bflo(sv.y), s3 = bfhi(sv.y);
    float di = dinv[i];
    float l0 = di * (s0 + a0), l1 = di * (s1 + a1);
    float l2 = di * (s2 + a2), l3 = di * (s3 + a3);

    float ol0 = fmaxf(l0, 0.f), ol1 = fmaxf(l1, 0.f);
    float ol2 = fmaxf(l2, 0.f), ol3 = fmaxf(l3, 0.f);
    float oh0 = fmaxf(s0 - l0, 0.f), oh1 = fmaxf(s1 - l1, 0.f);
    float oh2 = fmaxf(s2 - l2, 0.f), oh3 = fmaxf(s3 - l3, 0.f);

    int c0 = ((lane >> 4) << 6) + (lane & 15);   // true feat of q=0

    float om0 = 0.f, om1 = 0.f, om2 = 0.f, om3 = 0.f;
    float prA, prM = 0.f;
    if (lane < 32) {
        uint2 hv = *(const uint2*)(HmP + (size_t)i * 128 + off4);
        om0 = fmaxf(bflo(hv.x), 0.f); om1 = fmaxf(bfhi(hv.x), 0.f);
        om2 = fmaxf(bflo(hv.y), 0.f); om3 = fmaxf(bfhi(hv.y), 0.f);
        prA = ol0 * al[c0] + ol1 * al[c0 + 16] + ol2 * al[c0 + 32] + ol3 * al[c0 + 48];
        prM = om0 * am[c0] + om1 * am[c0 + 16] + om2 * am[c0 + 32] + om3 * am[c0 + 48];
    } else {
        int ch = c0 - 128;
        prA = oh0 * ah[ch] + oh1 * ah[ch + 16] + oh2 * ah[ch + 32] + oh3 * ah[ch + 48];
    }

#pragma unroll
    for (int d = 1; d < 32; d <<= 1) prA += __shfl_xor(prA, d);
#pragma unroll
    for (int d = 1; d < 32; d <<= 1) prM += __shfl_xor(prM, d);
    float g0 = __shfl(prA, 0);
    float g1 = __shfl(prA, 32);
    float g2 = __shfl(prM, 0);

    float sg0 = sigmoidf_(g0), sg1 = sigmoidf_(g1), sg2 = sigmoidf_(g2);
    const float inv3 = (1.0f / 3.0f);
    float e0 = (sg0 * att[0] + sg1 * att[3] + sg2 * att[6]) * inv3;
    float e1 = (sg0 * att[1] + sg1 * att[4] + sg2 * att[7]) * inv3;
    float e2 = (sg0 * att[2] + sg1 * att[5] + sg2 * att[8]) * inv3;
    float mx = fmaxf(e0, fmaxf(e1, e2));
    float x0 = expf(e0 - mx), x1 = expf(e1 - mx), x2 = expf(e2 - mx);
    float inv = 1.0f / (x0 + x1 + x2);
    float c0f = 3.0f * inv * x0, c1f = 3.0f * inv * x1, c2f = 3.0f * inv * x2;

    int src = lane | 32;
    float th0 = __shfl(oh0, src), th1 = __shfl(oh1, src);
    float th2 = __shfl(oh2, src), th3 = __shfl(oh3, src);

    if (lane < 32) {
        // hbuf permuted: pos p = lane*4+q -> true feat c_q (matches W1t k-perm)
        ushort4v o;
        o[0] = f2bf(c0f * ol0 + c1f * th0 + c2f * om0);
        o[1] = f2bf(c0f * ol1 + c1f * th1 + c2f * om1);
        o[2] = f2bf(c0f * ol2 + c1f * th2 + c2f * om2);
        o[3] = f2bf(c0f * ol3 + c1f * th3 + c2f * om3);
        *(ushort4v*)&hout[(size_t)i * 128 + off4] = o;
    }
}

// ---------------- layer 1: wave-per-node, shfl-decoupled fp8 gather + ACM epilogue ----------------
// H1q fp8 plain [80 B/row]; H1g bf16 plain [80] (self); H1m bf16 [40].

__global__ __launch_bounds__(256) void k_layer1(
        const unsigned short* __restrict__ H1g, const unsigned char* __restrict__ H1q,
        const unsigned short* __restrict__ H1m,
        const int* __restrict__ rowPtr, const unsigned short* __restrict__ colIdx,
        const float* __restrict__ dinv,
        const float* __restrict__ al, const float* __restrict__ ah,
        const float* __restrict__ am, const float* __restrict__ att,
        float* __restrict__ out) {
    int lane = threadIdx.x & 63;
    int i = blockIdx.x * 4 + (threadIdx.x >> 6);

    int p0 = rfl(rowPtr[i]);
    int p1 = rfl(rowPtr[i + 1]);
    int deg = p1 - p0;
    float a0 = 0.f, a1 = 0.f, a2 = 0.f, a3 = 0.f;
    bool active = lane < 20;
    int off4 = lane * 4;
    int offc = active ? off4 : 0;    // clamp: inactive lanes load safely in-row

    auto gath = [&](int js) -> unsigned {
        return *(const unsigned*)(H1q + (size_t)((unsigned)js * 80u) + offc);
    };
    auto addw = [&](unsigned w) {
        f32x2 d0 = __builtin_amdgcn_cvt_pk_f32_fp8((int)w, false);
        f32x2 d1 = __builtin_amdgcn_cvt_pk_f32_fp8((int)w, true);
        a0 += d0.x; a1 += d0.y; a2 += d1.x; a3 += d1.y;
    };

    for (int c = 0; c < deg; c += 64) {
        int rem = deg - c; if (rem > 64) rem = 64;
        int mycol = (int)colIdx[p0 + c + (lane < rem ? lane : 0)];
        int q = 0;
        for (; q + 7 < rem; q += 8) {
            int j0 = rfl(__shfl(mycol, q + 0));
            int j1 = rfl(__shfl(mycol, q + 1));
            int j2 = rfl(__shfl(mycol, q + 2));
            int j3 = rfl(__shfl(mycol, q + 3));
            int j4 = rfl(__shfl(mycol, q + 4));
            int j5 = rfl(__shfl(mycol, q + 5));
            int j6 = rfl(__shfl(mycol, q + 6));
            int j7 = rfl(__shfl(mycol, q + 7));
            unsigned w0 = gath(j0), w1 = gath(j1), w2 = gath(j2), w3 = gath(j3);
            unsigned w4 = gath(j4), w5 = gath(j5), w6 = gath(j6), w7 = gath(j7);
            addw(w0); addw(w1); addw(w2); addw(w3);
            addw(w4); addw(w5); addw(w6); addw(w7);
        }
        for (; q < rem; ++q) {
            int j = rfl(__shfl(mycol, q));
            addw(gath(j));
        }
    }

    float s0 = 0.f, s1 = 0.f, s2 = 0.f, s3 = 0.f;
    if (active) {
        uint2 sv = *(const uint2*)(H1g + (size_t)i * 80 + off4);  // 4 bf16 self
        s0 = bflo(sv.x); s1 = bfhi(sv.x); s2 = bflo(sv.y); s3 = bfhi(sv.y);
    }
    float di = dinv[i];
    float l0 = di * (s0 + a0), l1 = di * (s1 + a1);
    float l2 = di * (s2 + a2), l3 = di * (s3 + a3);

    float ol0 = fmaxf(l0, 0.f), ol1 = fmaxf(l1, 0.f);
    float ol2 = fmaxf(l2, 0.f), ol3 = fmaxf(l3, 0.f);
    float oh0 = fmaxf(s0 - l0, 0.f), oh1 = fmaxf(s1 - l1, 0.f);
    float oh2 = fmaxf(s2 - l2, 0.f), oh3 = fmaxf(s3 - l3, 0.f);

    float om0 = 0.f, om1 = 0.f, om2 = 0.f, om3 = 0.f;
    float r0 = 0.f, r1 = 0.f, r2 = 0.f;
    if (lane < 10) {
        uint2 hv = *(const uint2*)(H1m + (size_t)i * 40 + off4);
        om0 = fmaxf(bflo(hv.x), 0.f); om1 = fmaxf(bfhi(hv.x), 0.f);
        om2 = fmaxf(bflo(hv.y), 0.f); om3 = fmaxf(bfhi(hv.y), 0.f);
        float4 alv = *(const float4*)(al + off4);
        float4 amv = *(const float4*)(am + off4);
        r0 = ol0 * alv.x + ol1 * alv.y + ol2 * alv.z + ol3 * alv.w;
        r2 = om0 * amv.x + om1 * amv.y + om2 * amv.z + om3 * amv.w;
    } else if (lane < 20) {
        float4 ahv = *(const float4*)(ah + (off4 - 40));
        r1 = oh0 * ahv.x + oh1 * ahv.y + oh2 * ahv.z + oh3 * ahv.w;
    }

#pragma unroll
    for (int d = 1; d < 64; d <<= 1) r0 += __shfl_xor(r0, d);
#pragma unroll
    for (int d = 1; d < 64; d <<= 1) r1 += __shfl_xor(r1, d);
#pragma unroll
    for (int d = 1; d < 64; d <<= 1) r2 += __shfl_xor(r2, d);

    float sg0 = sigmoidf_(r0), sg1 = sigmoidf_(r1), sg2 = sigmoidf_(r2);
    const float inv3 = (1.0f / 3.0f);
    float e0 = (sg0 * att[0] + sg1 * att[3] + sg2 * att[6]) * inv3;
    float e1 = (sg0 * att[1] + sg1 * att[4] + sg2 * att[7]) * inv3;
    float e2 = (sg0 * att[2] + sg1 * att[5] + sg2 * att[8]) * inv3;
    float mx = fmaxf(e0, fmaxf(e1, e2));
    float x0 = expf(e0 - mx), x1 = expf(e1 - mx), x2 = expf(e2 - mx);
    float inv = 1.0f / (x0 + x1 + x2);
    float c0 = 3.0f * inv * x0, c1 = 3.0f * inv * x1, c2 = 3.0f * inv * x2;

    // oh for output feat f (=4l+k) lives on lane l+10, same k
    int src = (lane + 10) & 63;
    float th0 = __shfl(oh0, src), th1 = __shfl(oh1, src);
    float th2 = __shfl(oh2, src), th3 = __shfl(oh3, src);

    if (lane < 10) {
        float4 o;
        o.x = c0 * ol0 + c1 * th0 + c2 * om0;
        o.y = c0 * ol1 + c1 * th1 + c2 * om1;
        o.z = c0 * ol2 + c1 * th2 + c2 * om2;
        o.w = c0 * ol3 + c1 * th3 + c2 * om3;
        *(float4*)&out[(size_t)i * 40 + off4] = o;
    }
}

// ---------------- launch ----------------

extern "C" void kernel_launch(void* const* d_in, const int* in_sizes, int n_in,
                              void* d_out, int out_size, void* d_ws, size_t ws_size,
                              hipStream_t stream) {
    const float* x    = (const float*)d_in[0];
    const int*   ei   = (const int*)d_in[1];
    const float* Wl0  = (const float*)d_in[2];
    const float* Wh0  = (const float*)d_in[3];
    const float* Wm0  = (const float*)d_in[4];
    const float* al0  = (const float*)d_in[5];
    const float* ah0  = (const float*)d_in[6];
    const float* am0  = (const float*)d_in[7];
    const float* att0 = (const float*)d_in[8];
    const float* Wl1  = (const float*)d_in[9];
    const float* Wh1  = (const float*)d_in[10];
    const float* Wm1  = (const float*)d_in[11];
    const float* al1  = (const float*)d_in[12];
    const float* ah1  = (const float*)d_in[13];
    const float* am1  = (const float*)d_in[14];
    const float* att1 = (const float*)d_in[15];
    float* out = (float*)d_out;

    char* ws = (char*)d_ws;
    size_t off = 0;
    auto alloc = [&](size_t bytes) -> char* {
        char* p = ws + off;
        off += (bytes + 255) & ~(size_t)255;
        return p;
    };
    int*      rowPtr  = (int*)     alloc((size_t)(N_NODES + 1) * 4);
    int*      blkTot  = (int*)     alloc(256 * 4);
    unsigned* segHist = (unsigned*)alloc((size_t)SEG * NWORD * 4);   // 12.8 MB
    unsigned short* rank   = (unsigned short*)alloc((size_t)N_EDGES * 2);
    unsigned*       rc     = (unsigned*)      alloc((size_t)N_EDGES * 4);
    unsigned short* colIdx = (unsigned short*)alloc((size_t)N_EDGES * 2 + 256);
    float* dinv   = (float*)alloc((size_t)N_NODES * 4);
    unsigned short* W0t  = (unsigned short*)alloc((size_t)W0N * IN_F * 2);
    unsigned short* W1t  = (unsigned short*)alloc((size_t)W1N * HID_F * 2);
    unsigned short* xb   = (unsigned short*)alloc((size_t)N_NODES * IN_F * 2);
    unsigned short* Hs   = (unsigned short*)alloc((size_t)N_NODES * 256 * 2);
    unsigned char*  Hq   = (unsigned char*) alloc((size_t)N_NODES * 256);
    unsigned short* HmP  = (unsigned short*)alloc((size_t)N_NODES * 128 * 2);
    unsigned short* H1g  = (unsigned short*)alloc((size_t)N_NODES * 80 * 2);
    unsigned char*  H1q  = (unsigned char*) alloc((size_t)N_NODES * 80 + 256);  // +pad
    unsigned short* H1m  = (unsigned short*)alloc((size_t)N_NODES * 40 * 2);
    unsigned short* hbuf = (unsigned short*)alloc((size_t)N_NODES * HID_F * 2);

    // 1. fused: segmented LDS histogram | x->bf16 | W packs
    k_hp<<<HPREPB, 256, 0, stream>>>(ei, segHist, rank, rc,
                                     x, xb, Wl0, Wh0, Wm0, W0t,
                                     Wl1, Wh1, Wm1, W1t);
    // 2. segment-offset scan + local rowPtr + dinv
    k_scanseg<<<WB, 256, 0, stream>>>(segHist, rowPtr, dinv, blkTot);
    // 3-4. block-offset scan + apply
    k_scan2<<<1, 256, 0, stream>>>(blkTot);
    k_scan3<<<NB, 256, 0, stream>>>(blkTot, rowPtr);
    // 5. GEMM0 (layer-0 epilogue: Hs/Hq/HmP) with fused atomic-free CSR fill
    {
        dim3 grid(3 + 8, (N_NODES + 127) / 128);
        k_gemm_fill<1><<<grid, 256, 0, stream>>>(xb, W0t,
                                                 nullptr, 0, nullptr, 0, 0, nullptr,
                                                 Hs, Hq, HmP,
                                                 N_NODES, W0N, IN_F, 3,
                                                 rc, rank, rowPtr,
                                                 (const unsigned short*)segHist, colIdx);
    }
    // 6. layer-0 aggregate + epilogue (1 wave per node, R11-exact)
    k_layer0<<<N_NODES / 4, 256, 0, stream>>>(Hs, Hq, HmP, rowPtr, colIdx, dinv,
                                              al0, ah0, am0, att0, hbuf);
    // 7. GEMM1 (bf16 H1g/H1m + fp8 H1q)
    {
        dim3 grid(1, (N_NODES + 127) / 128);
        k_gemm_fill<0><<<grid, 256, 0, stream>>>(hbuf, W1t,
                                                 H1g, 80, H1m, 40, 80, H1q,
                                                 nullptr, nullptr, nullptr,
                                                 N_NODES, W1N, HID_F, 1,
                                                 nullptr, nullptr, nullptr, nullptr, nullptr);
    }
    // 8. layer-1 aggregate + epilogue
    k_layer1<<<N_NODES / 4, 256, 0, stream>>>(H1g, H1q, H1m, rowPtr, colIdx, dinv,
                                              al1, ah1, am1, att1, out);
}

// Round 17
// 186.414 us; speedup vs baseline: 1.0038x; 1.0017x over previous
//
#include <hip/hip_runtime.h>
#include <math.h>

#define N_NODES 50000
#define N_EDGES 800000
#define IN_F    256
#define HID_F   128
#define OUT_F   40
#define W0N     (3*HID_F)   // 384
#define W1N     (3*OUT_F)   // 120
#define NB      ((N_NODES + 255) / 256)   // 196

#define SEG     128
#define EPB     (N_EDGES / SEG)           // 6250 edges per segment
#define NWORD   (N_NODES / 2)             // 25000 packed words (2 nodes/word)
#define WB      ((NWORD + 255) / 256)     // 98 scanseg blocks

// k_hp block ranges: [0,SEG) hist | x convert | pack W0 | pack W1
#define XB   ((N_NODES * IN_F) / (256 * 16))   // 3125
#define P0B  ((IN_F * W0N) / 256)              // 384
#define P1B  ((HID_F * W1N) / 256)             // 60
#define HPB0 (SEG)
#define HPB1 (SEG + XB)
#define HPB2 (SEG + XB + P0B)
#define HPREPB (SEG + XB + P0B + P1B)          // 3697

typedef __attribute__((ext_vector_type(8))) unsigned short ushort8;
typedef __attribute__((ext_vector_type(4))) unsigned short ushort4v;
typedef __attribute__((ext_vector_type(8))) __bf16 bf16x8;
typedef __attribute__((ext_vector_type(4))) float f32x4;
typedef __attribute__((ext_vector_type(2))) float f32x2;

static __device__ __forceinline__ float sigmoidf_(float x) {
    return 1.0f / (1.0f + expf(-x));
}

static __device__ __forceinline__ unsigned short f2bf(float f) {
    unsigned u = __float_as_uint(f);
    u += 0x7FFFu + ((u >> 16) & 1u);
    return (unsigned short)(u >> 16);
}

static __device__ __forceinline__ float bflo(unsigned u) { return __uint_as_float(u << 16); }
static __device__ __forceinline__ float bfhi(unsigned u) { return __uint_as_float(u & 0xffff0000u); }
static __device__ __forceinline__ int rfl(int v) { return __builtin_amdgcn_readfirstlane(v); }

// ------- fused: segmented LDS histogram | x->bf16 | pack W0^T | pack W1^T(k-perm) -------

__global__ __launch_bounds__(256) void k_hp(
        const int* __restrict__ ei, unsigned* __restrict__ segHist,
        unsigned short* __restrict__ rank, unsigned* __restrict__ rc,
        const float* __restrict__ x, unsigned short* __restrict__ xb,
        const float* __restrict__ Wl0, const float* __restrict__ Wh0,
        const float* __restrict__ Wm0, unsigned short* __restrict__ W0t,
        const float* __restrict__ Wl1, const float* __restrict__ Wh1,
        const float* __restrict__ Wm1, unsigned short* __restrict__ W1t) {
    __shared__ unsigned hist[NWORD];   // 100 KB (only hist blocks touch it)
    int b = blockIdx.x, t = threadIdx.x;
    if (b < SEG) {
        int seg = b;
        for (int i = t; i < NWORD; i += 256) hist[i] = 0;
        __syncthreads();
        int base = seg * EPB;
        for (int k = t; k < EPB; k += 256) {
            int e = base + k;
            int r = ei[e];
            int c = ei[N_EDGES + e];
            unsigned old = atomicAdd(&hist[r >> 1], (r & 1) ? 0x10000u : 1u);
            unsigned lr = (r & 1) ? (old >> 16) : (old & 0xffffu);
            rank[e] = (unsigned short)lr;
            rc[e] = ((unsigned)r << 16) | (unsigned)c;
        }
        __syncthreads();
        unsigned* dst = segHist + (size_t)seg * NWORD;
        for (int i = t; i < NWORD; i += 256) dst[i] = hist[i];
    } else if (b < HPB1) {
        size_t idx = (size_t)(b - HPB0) * 4096 + t * 16;
        float4 f0 = *(const float4*)(x + idx);
        float4 f1 = *(const float4*)(x + idx + 4);
        float4 f2 = *(const float4*)(x + idx + 8);
        float4 f3 = *(const float4*)(x + idx + 12);
        ushort8 u0, u1;
        u0[0]=f2bf(f0.x); u0[1]=f2bf(f0.y); u0[2]=f2bf(f0.z); u0[3]=f2bf(f0.w);
        u0[4]=f2bf(f1.x); u0[5]=f2bf(f1.y); u0[6]=f2bf(f1.z); u0[7]=f2bf(f1.w);
        u1[0]=f2bf(f2.x); u1[1]=f2bf(f2.y); u1[2]=f2bf(f2.z); u1[3]=f2bf(f2.w);
        u1[4]=f2bf(f3.x); u1[5]=f2bf(f3.y); u1[6]=f2bf(f3.z); u1[7]=f2bf(f3.w);
        *(ushort8*)(xb + idx)     = u0;
        *(ushort8*)(xb + idx + 8) = u1;
    } else if (b < HPB2) {
        int i = (b - HPB1) * 256 + t;
        int n = i / IN_F, k = i % IN_F;
        float v;
        if (n < HID_F)            v = Wl0[k * HID_F + n];
        else if (n < 2 * HID_F)   v = Wh0[k * HID_F + (n - HID_F)];
        else                      v = Wm0[k * HID_F + (n - 2 * HID_F)];
        W0t[i] = f2bf(v);
    } else {
        int i = (b - HPB2) * 256 + t;
        int n = i / HID_F, kp = i % HID_F;
        // k-dim permuted to match hbuf's permuted layout: feat = g*64 + q*16 + c
        int k = ((kp >> 6) << 6) + ((kp & 3) << 4) + ((kp >> 2) & 15);
        float v;
        if (n < OUT_F)            v = Wl1[k * OUT_F + n];
        else if (n < 2 * OUT_F)   v = Wh1[k * OUT_F + (n - OUT_F)];
        else                      v = Wm1[k * OUT_F + (n - 2 * OUT_F)];
        W1t[i] = f2bf(v);
    }
}

// ------- scanseg: in-place segHist -> per-segment offsets; local rowPtr + dinv + blkTot -------

__global__ __launch_bounds__(256) void k_scanseg(
        unsigned* __restrict__ segHist, int* __restrict__ rowPtr,
        float* __restrict__ dinv, int* __restrict__ blkTot) {
    __shared__ int s[256];
    int t = threadIdx.x;
    int w = blockIdx.x * 256 + t;    // packed word = nodes 2w, 2w+1
    int cum0 = 0, cum1 = 0;
    if (w < NWORD) {
        for (int sg = 0; sg < SEG; ++sg) {
            size_t idx = (size_t)sg * NWORD + w;
            unsigned h = segHist[idx];
            segHist[idx] = ((unsigned)cum1 << 16) | (unsigned)cum0;  // offset-before
            cum0 += (int)(h & 0xffffu);
            cum1 += (int)(h >> 16);
        }
    }
    int deg0 = cum0, deg1 = cum1;
    int pair = deg0 + deg1;
    s[t] = pair; __syncthreads();
    for (int d = 1; d < 256; d <<= 1) {
        int x = (t >= d) ? s[t - d] : 0;
        __syncthreads();
        s[t] += x;
        __syncthreads();
    }
    int basep = s[t] - pair;   // exclusive prefix within block
    if (w < NWORD) {
        rowPtr[2 * w]     = basep;
        rowPtr[2 * w + 1] = basep + deg0;
        dinv[2 * w]     = 1.0f / (1.0f + (float)deg0);
        dinv[2 * w + 1] = 1.0f / (1.0f + (float)deg1);
    }
    if (t == 255) blkTot[blockIdx.x] = s[255];
}

__global__ void k_scan2(int* __restrict__ blk) {
    __shared__ int s[256];
    int t = threadIdx.x;
    int v = (t < WB) ? blk[t] : 0;
    s[t] = v; __syncthreads();
    for (int d = 1; d < 256; d <<= 1) {
        int x = (t >= d) ? s[t - d] : 0;
        __syncthreads();
        s[t] += x;
        __syncthreads();
    }
    if (t < WB) blk[t] = s[t] - v;
}

__global__ void k_scan3(const int* __restrict__ blkOff, int* __restrict__ rowPtr) {
    int t = threadIdx.x;
    int gid = blockIdx.x * 256 + t;
    if (gid < N_NODES) rowPtr[gid] += blkOff[gid >> 9];   // 512 nodes per scanseg block
    if (gid == 0) rowPtr[N_NODES] = N_EDGES;
}

// ---------------- bf16 MFMA GEMM (reg double-buffered) + fused CSR-fill ----------------
// tile 128x128, BK=32, 4 waves (2x2).
// EPI=0 (GEMM1): bf16 split write + fp8 byte store to Cq for gn<nsplit.
// EPI=1 (GEMM0): Hs (bf16 perm), Hq (fp8 perm), HmP (bf16 perm).

#define BKP 40   // 32 + 8 pad

template<int EPI>
__global__ __launch_bounds__(256) void k_gemm_fill(
        const unsigned short* __restrict__ A, const unsigned short* __restrict__ Bt,
        unsigned short* __restrict__ C0, int ld0,
        unsigned short* __restrict__ C1, int ld1, int nsplit,
        unsigned char* __restrict__ Cq,
        unsigned short* __restrict__ Hs, unsigned char* __restrict__ Hq,
        unsigned short* __restrict__ HmP,
        int M, int N, int K, int nxt,
        const unsigned* __restrict__ rc, const unsigned short* __restrict__ rank,
        const int* __restrict__ rowPtr, const unsigned short* __restrict__ segOff,
        unsigned short* __restrict__ colIdx) {
    __shared__ unsigned short As[128 * BKP];
    __shared__ unsigned short Bs[128 * BKP];
    int tid  = threadIdx.x;

    if ((int)blockIdx.x >= nxt) {
        int fid = (blockIdx.x - nxt) * gridDim.y + blockIdx.y;
        int e = fid * 256 + tid;
        if (e < N_EDGES) {
            unsigned x = rc[e];
            int r = (int)(x >> 16);
            int seg = e / EPB;
            int pos = rowPtr[r] + (int)segOff[(size_t)seg * N_NODES + r] + (int)rank[e];
            colIdx[pos] = (unsigned short)(x & 0xffffu);
        }
        return;
    }

    int lane = tid & 63, wid = tid >> 6;
    int wr = wid >> 1, wc = wid & 1;
    int bm = blockIdx.y * 128, bn = blockIdx.x * 128;

    int srow = tid >> 1;
    int scol = (tid & 1) * 16;

    int garow = min(bm + srow, M - 1);
    int gbrow = min(bn + srow, N - 1);

    f32x4 acc[4][4];
#pragma unroll
    for (int m = 0; m < 4; ++m)
#pragma unroll
        for (int n = 0; n < 4; ++n)
            acc[m][n] = (f32x4)(0.0f);

    int kg = (lane >> 4) * 8;
    int rA = wr * 64 + (lane & 15);
    int rB = wc * 64 + (lane & 15);

    const unsigned short* srcA = A + (size_t)garow * K + scol;
    const unsigned short* srcB = Bt + (size_t)gbrow * K + scol;
    ushort8 ra0 = *(const ushort8*)(srcA);
    ushort8 ra1 = *(const ushort8*)(srcA + 8);
    ushort8 rb0 = *(const ushort8*)(srcB);
    ushort8 rb1 = *(const ushort8*)(srcB + 8);

    for (int k0 = 0; k0 < K; k0 += 32) {
        *(ushort8*)&As[srow * BKP + scol]     = ra0;
        *(ushort8*)&As[srow * BKP + scol + 8] = ra1;
        *(ushort8*)&Bs[srow * BKP + scol]     = rb0;
        *(ushort8*)&Bs[srow * BKP + scol + 8] = rb1;
        __syncthreads();
        if (k0 + 32 < K) {   // prefetch next K-tile; flies during ds_read+MFMA
            ra0 = *(const ushort8*)(srcA + k0 + 32);
            ra1 = *(const ushort8*)(srcA + k0 + 40);
            rb0 = *(const ushort8*)(srcB + k0 + 32);
            rb1 = *(const ushort8*)(srcB + k0 + 40);
        }

        bf16x8 a[4], b[4];
#pragma unroll
        for (int m = 0; m < 4; ++m)
            a[m] = __builtin_bit_cast(bf16x8, *(const ushort8*)&As[(rA + m * 16) * BKP + kg]);
#pragma unroll
        for (int n = 0; n < 4; ++n)
            b[n] = __builtin_bit_cast(bf16x8, *(const ushort8*)&Bs[(rB + n * 16) * BKP + kg]);
#pragma unroll
        for (int m = 0; m < 4; ++m)
#pragma unroll
            for (int n = 0; n < 4; ++n)
                acc[m][n] = __builtin_amdgcn_mfma_f32_16x16x32_bf16(a[m], b[n], acc[m][n], 0, 0, 0);
        __syncthreads();
    }

    int col  = lane & 15;
    int rsub = (lane >> 4) * 4;

    if (EPI == 0) {
#pragma unroll
        for (int m = 0; m < 4; ++m) {
            int gm0 = bm + wr * 64 + m * 16 + rsub;
#pragma unroll
            for (int n = 0; n < 4; ++n) {
                int gn = bn + wc * 64 + n * 16 + col;
                if (gn >= N) continue;
#pragma unroll
                for (int j = 0; j < 4; ++j) {
                    int gm = gm0 + j;
                    if (gm >= M) continue;
                    float v = acc[m][n][j];
                    unsigned short b = f2bf(v);
                    if (gn < nsplit) {
                        C0[(size_t)gm * ld0 + gn] = b;
                        int pk = __builtin_amdgcn_cvt_pk_fp8_f32(v, v, 0, false);
                        Cq[(size_t)gm * nsplit + gn] = (unsigned char)(pk & 0xff);
                    } else {
                        C1[(size_t)gm * ld1 + (gn - nsplit)] = b;
                    }
                }
            }
        }
    } else {
        // permuted writes; this thread covers pos base = bn + wc*64 + col*4
#pragma unroll
        for (int m = 0; m < 4; ++m) {
            int gm0 = bm + wr * 64 + m * 16 + rsub;
#pragma unroll
            for (int j = 0; j < 4; ++j) {
                int gm = gm0 + j;
                if (gm >= M) continue;
                float v0 = acc[m][0][j], v1 = acc[m][1][j];
                float v2 = acc[m][2][j], v3 = acc[m][3][j];
                ushort4v o;
                o[0] = f2bf(v0); o[1] = f2bf(v1); o[2] = f2bf(v2); o[3] = f2bf(v3);
                if (bn < 256) {
                    int pos = bn + wc * 64 + col * 4;
                    *(ushort4v*)&Hs[(size_t)gm * 256 + pos] = o;
                    int pk = 0;
                    pk = __builtin_amdgcn_cvt_pk_fp8_f32(v0, v1, pk, false);
                    pk = __builtin_amdgcn_cvt_pk_fp8_f32(v2, v3, pk, true);
                    *(unsigned*)&Hq[(size_t)gm * 256 + pos] = (unsigned)pk;
                } else {
                    int pos = wc * 64 + col * 4;
                    *(ushort4v*)&HmP[(size_t)gm * 128 + pos] = o;
                }
            }
        }
    }
}

// ---------------- layer 0: wave-per-node, shfl-decoupled fp8 gather + ACM epilogue ----------------
// (R11-exact version: best measured 50.5 us)
// Hq fp8 perm [256 B/row]; Hs bf16 perm [256]; HmP bf16 perm [128].

__global__ __launch_bounds__(256) void k_layer0(
        const unsigned short* __restrict__ Hs, const unsigned char* __restrict__ Hq,
        const unsigned short* __restrict__ HmP,
        const int* __restrict__ rowPtr, const unsigned short* __restrict__ colIdx,
        const float* __restrict__ dinv,
        const float* __restrict__ al, const float* __restrict__ ah,
        const float* __restrict__ am, const float* __restrict__ att,
        unsigned short* __restrict__ hout) {
    int lane = threadIdx.x & 63;
    int i = blockIdx.x * 4 + (threadIdx.x >> 6);

    int p0 = rfl(rowPtr[i]);
    int p1 = rfl(rowPtr[i + 1]);
    int deg = p1 - p0;
    float a0 = 0.f, a1 = 0.f, a2 = 0.f, a3 = 0.f;
    int off4 = lane * 4;

    auto gath = [&](int js) -> unsigned {
        return *(const unsigned*)(Hq + ((size_t)(unsigned)js << 8) + off4);
    };
    auto addw = [&](unsigned w) {
        f32x2 d0 = __builtin_amdgcn_cvt_pk_f32_fp8((int)w, false);
        f32x2 d1 = __builtin_amdgcn_cvt_pk_f32_fp8((int)w, true);
        a0 += d0.x; a1 += d0.y; a2 += d1.x; a3 += d1.y;
    };

    for (int c = 0; c < deg; c += 64) {
        int rem = deg - c; if (rem > 64) rem = 64;
        int mycol = (int)colIdx[p0 + c + (lane < rem ? lane : 0)];
        int q = 0;
        for (; q + 7 < rem; q += 8) {
            int j0 = rfl(__shfl(mycol, q + 0));
            int j1 = rfl(__shfl(mycol, q + 1));
            int j2 = rfl(__shfl(mycol, q + 2));
            int j3 = rfl(__shfl(mycol, q + 3));
            int j4 = rfl(__shfl(mycol, q + 4));
            int j5 = rfl(__shfl(mycol, q + 5));
            int j6 = rfl(__shfl(mycol, q + 6));
            int j7 = rfl(__shfl(mycol, q + 7));
            unsigned w0 = gath(j0), w1 = gath(j1), w2 = gath(j2), w3 = gath(j3);
            unsigned w4 = gath(j4), w5 = gath(j5), w6 = gath(j6), w7 = gath(j7);
            addw(w0); addw(w1); addw(w2); addw(w3);
            addw(w4); addw(w5); addw(w6); addw(w7);
        }
        for (; q < rem; ++q) {
            int j = rfl(__shfl(mycol, q));
            addw(gath(j));
        }
    }

    uint2 sv = *(const uint2*)(Hs + (size_t)i * 256 + off4);   // 4 bf16 self vals
    float s0 = bflo(sv.x), s1 = bfhi(sv.x), s2 = bflo(sv.y), s3 = bfhi(sv.y);
    float di = dinv[i];
    float l0 = di * (s0 + a0), l1 = di * (s1 + a1);
    float l2 = di * (s2 + a2), l3 = di * (s3 + a3);

    float ol0 = fmaxf(l0, 0.f), ol1 = fmaxf(l1, 0.f);
    float ol2 = fmaxf(l2, 0.f), ol3 = fmaxf(l3, 0.f);
    float oh0 = fmaxf(s0 - l0, 0.f), oh1 = fmaxf(s1 - l1, 0.f);
    float oh2 = fmaxf(s2 - l2, 0.f), oh3 = fmaxf(s3 - l3, 0.f);

    int c0 = ((lane >> 4) << 6) + (lane & 15);   // true feat of q=0

    float om0 = 0.f, om1 = 0.f, om2 = 0.f, om3 = 0.f;
    float prA, prM = 0.f;
    if (lane < 32) {
        uint2 hv = *(const uint2*)(HmP + (size_t)i * 128 + off4);
        om0 = fmaxf(bflo(hv.x), 0.f); om1 = fmaxf(bfhi(hv.x), 0.f);
        om2 = fmaxf(bflo(hv.y), 0.f); om3 = fmaxf(bfhi(hv.y), 0.f);
        prA = ol0 * al[c0] + ol1 * al[c0 + 16] + ol2 * al[c0 + 32] + ol3 * al[c0 + 48];
        prM = om0 * am[c0] + om1 * am[c0 + 16] + om2 * am[c0 + 32] + om3 * am[c0 + 48];
    } else {
        int ch = c0 - 128;
        prA = oh0 * ah[ch] + oh1 * ah[ch + 16] + oh2 * ah[ch + 32] + oh3 * ah[ch + 48];
    }

#pragma unroll
    for (int d = 1; d < 32; d <<= 1) prA += __shfl_xor(prA, d);
#pragma unroll
    for (int d = 1; d < 32; d <<= 1) prM += __shfl_xor(prM, d);
    float g0 = __shfl(prA, 0);
    float g1 = __shfl(prA, 32);
    float g2 = __shfl(prM, 0);

    float sg0 = sigmoidf_(g0), sg1 = sigmoidf_(g1), sg2 = sigmoidf_(g2);
    const float inv3 = (1.0f / 3.0f);
    float e0 = (sg0 * att[0] + sg1 * att[3] + sg2 * att[6]) * inv3;
    float e1 = (sg0 * att[1] + sg1 * att[4] + sg2 * att[7]) * inv3;
    float e2 = (sg0 * att[2] + sg1 * att[5] + sg2 * att[8]) * inv3;
    float mx = fmaxf(e0, fmaxf(e1, e2));
    float x0 = expf(e0 - mx), x1 = expf(e1 - mx), x2 = expf(e2 - mx);
    float inv = 1.0f / (x0 + x1 + x2);
    float c0f = 3.0f * inv * x0, c1f = 3.0f * inv * x1, c2f = 3.0f * inv * x2;

    int src = lane | 32;
    float th0 = __shfl(oh0, src), th1 = __shfl(oh1, src);
    float th2 = __shfl(oh2, src), th3 = __shfl(oh3, src);

    if (lane < 32) {
        // hbuf permuted: pos p = lane*4+q -> true feat c_q (matches W1t k-perm)
        ushort4v o;
        o[0] = f2bf(c0f * ol0 + c1f * th0 + c2f * om0);
        o[1] = f2bf(c0f * ol1 + c1f * th1 + c2f * om1);
        o[2] = f2bf(c0f * ol2 + c1f * th2 + c2f * om2);
        o[3] = f2bf(c0f * ol3 + c1f * th3 + c2f * om3);
        *(ushort4v*)&hout[(size_t)i * 128 + off4] = o;
    }
}

// ---------------- layer 1: wave-per-node, shfl-decoupled fp8 gather + ACM epilogue ----------------
// H1q fp8 plain [80 B/row]; H1g bf16 plain [80] (self); H1m bf16 [40].

__global__ __launch_bounds__(256) void k_layer1(
        const unsigned short* __restrict__ H1g, const unsigned char* __restrict__ H1q,
        const unsigned short* __restrict__ H1m,
        const int* __restrict__ rowPtr, const unsigned short* __restrict__ colIdx,
        const float* __restrict__ dinv,
        const float* __restrict__ al, const float* __restrict__ ah,
        const float* __restrict__ am, const float* __restrict__ att,
        float* __restrict__ out) {
    int lane = threadIdx.x & 63;
    int i = blockIdx.x * 4 + (threadIdx.x >> 6);

    int p0 = rfl(rowPtr[i]);
    int p1 = rfl(rowPtr[i + 1]);
    int deg = p1 - p0;
    float a0 = 0.f, a1 = 0.f, a2 = 0.f, a3 = 0.f;
    bool active = lane < 20;
    int off4 = lane * 4;
    int offc = active ? off4 : 0;    // clamp: inactive lanes load safely in-row

    auto gath = [&](int js) -> unsigned {
        return *(const unsigned*)(H1q + (size_t)((unsigned)js * 80u) + offc);
    };
    auto addw = [&](unsigned w) {
        f32x2 d0 = __builtin_amdgcn_cvt_pk_f32_fp8((int)w, false);
        f32x2 d1 = __builtin_amdgcn_cvt_pk_f32_fp8((int)w, true);
        a0 += d0.x; a1 += d0.y; a2 += d1.x; a3 += d1.y;
    };

    for (int c = 0; c < deg; c += 64) {
        int rem = deg - c; if (rem > 64) rem = 64;
        int mycol = (int)colIdx[p0 + c + (lane < rem ? lane : 0)];
        int q = 0;
        for (; q + 7 < rem; q += 8) {
            int j0 = rfl(__shfl(mycol, q + 0));
            int j1 = rfl(__shfl(mycol, q + 1));
            int j2 = rfl(__shfl(mycol, q + 2));
            int j3 = rfl(__shfl(mycol, q + 3));
            int j4 = rfl(__shfl(mycol, q + 4));
            int j5 = rfl(__shfl(mycol, q + 5));
            int j6 = rfl(__shfl(mycol, q + 6));
            int j7 = rfl(__shfl(mycol, q + 7));
            unsigned w0 = gath(j0), w1 = gath(j1), w2 = gath(j2), w3 = gath(j3);
            unsigned w4 = gath(j4), w5 = gath(j5), w6 = gath(j6), w7 = gath(j7);
            addw(w0); addw(w1); addw(w2); addw(w3);
            addw(w4); addw(w5); addw(w6); addw(w7);
        }
        for (; q < rem; ++q) {
            int j = rfl(__shfl(mycol, q));
            addw(gath(j));
        }
    }

    float s0 = 0.f, s1 = 0.f, s2 = 0.f, s3 = 0.f;
    if (active) {
        uint2 sv = *(const uint2*)(H1g + (size_t)i * 80 + off4);  // 4 bf16 self
        s0 = bflo(sv.x); s1 = bfhi(sv.x); s2 = bflo(sv.y); s3 = bfhi(sv.y);
    }
    float di = dinv[i];
    float l0 = di * (s0 + a0), l1 = di * (s1 + a1);
    float l2 = di * (s2 + a2), l3 = di * (s3 + a3);

    float ol0 = fmaxf(l0, 0.f), ol1 = fmaxf(l1, 0.f);
    float ol2 = fmaxf(l2, 0.f), ol3 = fmaxf(l3, 0.f);
    float oh0 = fmaxf(s0 - l0, 0.f), oh1 = fmaxf(s1 - l1, 0.f);
    float oh2 = fmaxf(s2 - l2, 0.f), oh3 = fmaxf(s3 - l3, 0.f);

    float om0 = 0.f, om1 = 0.f, om2 = 0.f, om3 = 0.f;
    float r0 = 0.f, r1 = 0.f, r2 = 0.f;
    if (lane < 10) {
        uint2 hv = *(const uint2*)(H1m + (size_t)i * 40 + off4);
        om0 = fmaxf(bflo(hv.x), 0.f); om1 = fmaxf(bfhi(hv.x), 0.f);
        om2 = fmaxf(bflo(hv.y), 0.f); om3 = fmaxf(bfhi(hv.y), 0.f);
        float4 alv = *(const float4*)(al + off4);
        float4 amv = *(const float4*)(am + off4);
        r0 = ol0 * alv.x + ol1 * alv.y + ol2 * alv.z + ol3 * alv.w;
        r2 = om0 * amv.x + om1 * amv.y + om2 * amv.z + om3 * amv.w;
    } else if (lane < 20) {
        float4 ahv = *(const float4*)(ah + (off4 - 40));
        r1 = oh0 * ahv.x + oh1 * ahv.y + oh2 * ahv.z + oh3 * ahv.w;
    }

#pragma unroll
    for (int d = 1; d < 64; d <<= 1) r0 += __shfl_xor(r0, d);
#pragma unroll
    for (int d = 1; d < 64; d <<= 1) r1 += __shfl_xor(r1, d);
#pragma unroll
    for (int d = 1; d < 64; d <<= 1) r2 += __shfl_xor(r2, d);

    float sg0 = sigmoidf_(r0), sg1 = sigmoidf_(r1), sg2 = sigmoidf_(r2);
    const float inv3 = (1.0f / 3.0f);
    float e0 = (sg0 * att[0] + sg1 * att[3] + sg2 * att[6]) * inv3;
    float e1 = (sg0 * att[1] + sg1 * att[4] + sg2 * att[7]) * inv3;
    float e2 = (sg0 * att[2] + sg1 * att[5] + sg2 * att[8]) * inv3;
    float mx = fmaxf(e0, fmaxf(e1, e2));
    float x0 = expf(e0 - mx), x1 = expf(e1 - mx), x2 = expf(e2 - mx);
    float inv = 1.0f / (x0 + x1 + x2);
    float c0 = 3.0f * inv * x0, c1 = 3.0f * inv * x1, c2 = 3.0f * inv * x2;

    // oh for output feat f (=4l+k) lives on lane l+10, same k
    int src = (lane + 10) & 63;
    float th0 = __shfl(oh0, src), th1 = __shfl(oh1, src);
    float th2 = __shfl(oh2, src), th3 = __shfl(oh3, src);

    if (lane < 10) {
        float4 o;
        o.x = c0 * ol0 + c1 * th0 + c2 * om0;
        o.y = c0 * ol1 + c1 * th1 + c2 * om1;
        o.z = c0 * ol2 + c1 * th2 + c2 * om2;
        o.w = c0 * ol3 + c1 * th3 + c2 * om3;
        *(float4*)&out[(size_t)i * 40 + off4] = o;
    }
}

// ---------------- launch ----------------

extern "C" void kernel_launch(void* const* d_in, const int* in_sizes, int n_in,
                              void* d_out, int out_size, void* d_ws, size_t ws_size,
                              hipStream_t stream) {
    const float* x    = (const float*)d_in[0];
    const int*   ei   = (const int*)d_in[1];
    const float* Wl0  = (const float*)d_in[2];
    const float* Wh0  = (const float*)d_in[3];
    const float* Wm0  = (const float*)d_in[4];
    const float* al0  = (const float*)d_in[5];
    const float* ah0  = (const float*)d_in[6];
    const float* am0  = (const float*)d_in[7];
    const float* att0 = (const float*)d_in[8];
    const float* Wl1  = (const float*)d_in[9];
    const float* Wh1  = (const float*)d_in[10];
    const float* Wm1  = (const float*)d_in[11];
    const float* al1  = (const float*)d_in[12];
    const float* ah1  = (const float*)d_in[13];
    const float* am1  = (const float*)d_in[14];
    const float* att1 = (const float*)d_in[15];
    float* out = (float*)d_out;

    char* ws = (char*)d_ws;
    size_t off = 0;
    auto alloc = [&](size_t bytes) -> char* {
        char* p = ws + off;
        off += (bytes + 255) & ~(size_t)255;
        return p;
    };
    int*      rowPtr  = (int*)     alloc((size_t)(N_NODES + 1) * 4);
    int*      blkTot  = (int*)     alloc(256 * 4);
    unsigned* segHist = (unsigned*)alloc((size_t)SEG * NWORD * 4);   // 12.8 MB
    unsigned short* rank   = (unsigned short*)alloc((size_t)N_EDGES * 2);
    unsigned*       rc     = (unsigned*)      alloc((size_t)N_EDGES * 4);
    unsigned short* colIdx = (unsigned short*)alloc((size_t)N_EDGES * 2 + 256);
    float* dinv   = (float*)alloc((size_t)N_NODES * 4);
    unsigned short* W0t  = (unsigned short*)alloc((size_t)W0N * IN_F * 2);
    unsigned short* W1t  = (unsigned short*)alloc((size_t)W1N * HID_F * 2);
    unsigned short* xb   = (unsigned short*)alloc((size_t)N_NODES * IN_F * 2);
    unsigned short* Hs   = (unsigned short*)alloc((size_t)N_NODES * 256 * 2);
    unsigned char*  Hq   = (unsigned char*) alloc((size_t)N_NODES * 256);
    unsigned short* HmP  = (unsigned short*)alloc((size_t)N_NODES * 128 * 2);
    unsigned short* H1g  = (unsigned short*)alloc((size_t)N_NODES * 80 * 2);
    unsigned char*  H1q  = (unsigned char*) alloc((size_t)N_NODES * 80 + 256);  // +pad
    unsigned short* H1m  = (unsigned short*)alloc((size_t)N_NODES * 40 * 2);
    unsigned short* hbuf = (unsigned short*)alloc((size_t)N_NODES * HID_F * 2);

    // 1. fused: segmented LDS histogram | x->bf16 | W packs
    k_hp<<<HPREPB, 256, 0, stream>>>(ei, segHist, rank, rc,
                                     x, xb, Wl0, Wh0, Wm0, W0t,
                                     Wl1, Wh1, Wm1, W1t);
    // 2. segment-offset scan + local rowPtr + dinv
    k_scanseg<<<WB, 256, 0, stream>>>(segHist, rowPtr, dinv, blkTot);
    // 3-4. block-offset scan + apply
    k_scan2<<<1, 256, 0, stream>>>(blkTot);
    k_scan3<<<NB, 256, 0, stream>>>(blkTot, rowPtr);
    // 5. GEMM0 (layer-0 epilogue: Hs/Hq/HmP) with fused atomic-free CSR fill
    {
        dim3 grid(3 + 8, (N_NODES + 127) / 128);
        k_gemm_fill<1><<<grid, 256, 0, stream>>>(xb, W0t,
                                                 nullptr, 0, nullptr, 0, 0, nullptr,
                                                 Hs, Hq, HmP,
                                                 N_NODES, W0N, IN_F, 3,
                                                 rc, rank, rowPtr,
                                                 (const unsigned short*)segHist, colIdx);
    }
    // 6. layer-0 aggregate + epilogue (1 wave per node, R11-exact)
    k_layer0<<<N_NODES / 4, 256, 0, stream>>>(Hs, Hq, HmP, rowPtr, colIdx, dinv,
                                              al0, ah0, am0, att0, hbuf);
    // 7. GEMM1 (bf16 H1g/H1m + fp8 H1q)
    {
        dim3 grid(1, (N_NODES + 127) / 128);
        k_gemm_fill<0><<<grid, 256, 0, stream>>>(hbuf, W1t,
                                                 H1g, 80, H1m, 40, 80, H1q,
                                                 nullptr, nullptr, nullptr,
                                                 N_NODES, W1N, HID_F, 1,
                                                 nullptr, nullptr, nullptr, nullptr, nullptr);
    }
    // 8. layer-1 aggregate + epilogue
    k_layer1<<<N_NODES / 4, 256, 0, stream>>>(H1g, H1q, H1m, rowPtr, colIdx, dinv,
                                              al1, ah1, am1, att1, out);
}

// Round 18
// 184.668 us; speedup vs baseline: 1.0133x; 1.0095x over previous
//
#include <hip/hip_runtime.h>
#include <math.h>

#define N_NODES 50000
#define N_EDGES 800000
#define IN_F    256
#define HID_F   128
#define OUT_F   40
#define W0N     (3*HID_F)   // 384
#define W1N     (3*OUT_F)   // 120
#define NB      ((N_NODES + 255) / 256)   // 196

#define SEG     128
#define EPB     (N_EDGES / SEG)           // 6250 edges per segment
#define NWORD   (N_NODES / 2)             // 25000 packed words (2 nodes/word)
#define WB      ((NWORD + 255) / 256)     // 98 scanseg blocks

// k_hp block ranges: [0,SEG) hist | x convert | pack W0 | pack W1
#define XB   ((N_NODES * IN_F) / (256 * 16))   // 3125
#define P0B  ((IN_F * W0N) / 256)              // 384
#define P1B  ((HID_F * W1N) / 256)             // 60
#define HPB0 (SEG)
#define HPB1 (SEG + XB)
#define HPB2 (SEG + XB + P0B)
#define HPREPB (SEG + XB + P0B + P1B)          // 3697

typedef __attribute__((ext_vector_type(8))) unsigned short ushort8;
typedef __attribute__((ext_vector_type(4))) unsigned short ushort4v;
typedef __attribute__((ext_vector_type(8))) __bf16 bf16x8;
typedef __attribute__((ext_vector_type(4))) float f32x4;
typedef __attribute__((ext_vector_type(2))) float f32x2;

static __device__ __forceinline__ float sigmoidf_(float x) {
    return 1.0f / (1.0f + expf(-x));
}

static __device__ __forceinline__ unsigned short f2bf(float f) {
    unsigned u = __float_as_uint(f);
    u += 0x7FFFu + ((u >> 16) & 1u);
    return (unsigned short)(u >> 16);
}

static __device__ __forceinline__ float bflo(unsigned u) { return __uint_as_float(u << 16); }
static __device__ __forceinline__ float bfhi(unsigned u) { return __uint_as_float(u & 0xffff0000u); }
static __device__ __forceinline__ int rfl(int v) { return __builtin_amdgcn_readfirstlane(v); }

// ------- fused: segmented LDS histogram | x->bf16 | pack W0^T | pack W1^T(k-perm) -------

__global__ __launch_bounds__(256) void k_hp(
        const int* __restrict__ ei, unsigned* __restrict__ segHist,
        unsigned short* __restrict__ rank, unsigned* __restrict__ rc,
        const float* __restrict__ x, unsigned short* __restrict__ xb,
        const float* __restrict__ Wl0, const float* __restrict__ Wh0,
        const float* __restrict__ Wm0, unsigned short* __restrict__ W0t,
        const float* __restrict__ Wl1, const float* __restrict__ Wh1,
        const float* __restrict__ Wm1, unsigned short* __restrict__ W1t) {
    __shared__ unsigned hist[NWORD];   // 100 KB (only hist blocks touch it)
    int b = blockIdx.x, t = threadIdx.x;
    if (b < SEG) {
        int seg = b;
        for (int i = t; i < NWORD; i += 256) hist[i] = 0;
        __syncthreads();
        int base = seg * EPB;
        for (int k2 = t; k2 < EPB / 2; k2 += 256) {   // 2 edges per iteration
            int e = base + k2 * 2;
            int2 rv = *(const int2*)(ei + e);
            int2 cv = *(const int2*)(ei + N_EDGES + e);
            unsigned o0 = atomicAdd(&hist[rv.x >> 1], (rv.x & 1) ? 0x10000u : 1u);
            unsigned l0 = (rv.x & 1) ? (o0 >> 16) : (o0 & 0xffffu);
            unsigned o1 = atomicAdd(&hist[rv.y >> 1], (rv.y & 1) ? 0x10000u : 1u);
            unsigned l1 = (rv.y & 1) ? (o1 >> 16) : (o1 & 0xffffu);
            ushort2 rk;
            rk.x = (unsigned short)l0; rk.y = (unsigned short)l1;
            *(ushort2*)(rank + e) = rk;
            uint2 rcv;
            rcv.x = ((unsigned)rv.x << 16) | (unsigned)cv.x;
            rcv.y = ((unsigned)rv.y << 16) | (unsigned)cv.y;
            *(uint2*)(rc + e) = rcv;
        }
        __syncthreads();
        unsigned* dst = segHist + (size_t)seg * NWORD;
        for (int i = t; i < NWORD; i += 256) dst[i] = hist[i];
    } else if (b < HPB1) {
        size_t idx = (size_t)(b - HPB0) * 4096 + t * 16;
        float4 f0 = *(const float4*)(x + idx);
        float4 f1 = *(const float4*)(x + idx + 4);
        float4 f2 = *(const float4*)(x + idx + 8);
        float4 f3 = *(const float4*)(x + idx + 12);
        ushort8 u0, u1;
        u0[0]=f2bf(f0.x); u0[1]=f2bf(f0.y); u0[2]=f2bf(f0.z); u0[3]=f2bf(f0.w);
        u0[4]=f2bf(f1.x); u0[5]=f2bf(f1.y); u0[6]=f2bf(f1.z); u0[7]=f2bf(f1.w);
        u1[0]=f2bf(f2.x); u1[1]=f2bf(f2.y); u1[2]=f2bf(f2.z); u1[3]=f2bf(f2.w);
        u1[4]=f2bf(f3.x); u1[5]=f2bf(f3.y); u1[6]=f2bf(f3.z); u1[7]=f2bf(f3.w);
        *(ushort8*)(xb + idx)     = u0;
        *(ushort8*)(xb + idx + 8) = u1;
    } else if (b < HPB2) {
        int i = (b - HPB1) * 256 + t;
        int n = i / IN_F, k = i % IN_F;
        float v;
        if (n < HID_F)            v = Wl0[k * HID_F + n];
        else if (n < 2 * HID_F)   v = Wh0[k * HID_F + (n - HID_F)];
        else                      v = Wm0[k * HID_F + (n - 2 * HID_F)];
        W0t[i] = f2bf(v);
    } else {
        int i = (b - HPB2) * 256 + t;
        int n = i / HID_F, kp = i % HID_F;
        // k-dim permuted to match hbuf's permuted layout: feat = g*64 + q*16 + c
        int k = ((kp >> 6) << 6) + ((kp & 3) << 4) + ((kp >> 2) & 15);
        float v;
        if (n < OUT_F)            v = Wl1[k * OUT_F + n];
        else if (n < 2 * OUT_F)   v = Wh1[k * OUT_F + (n - OUT_F)];
        else                      v = Wm1[k * OUT_F + (n - 2 * OUT_F)];
        W1t[i] = f2bf(v);
    }
}

// ------- scanseg: in-place segHist -> per-segment offsets; local rowPtr + dinv + blkTot -------

__global__ __launch_bounds__(256) void k_scanseg(
        unsigned* __restrict__ segHist, int* __restrict__ rowPtr,
        float* __restrict__ dinv, int* __restrict__ blkTot) {
    __shared__ int s[256];
    int t = threadIdx.x;
    int w = blockIdx.x * 256 + t;    // packed word = nodes 2w, 2w+1
    int cum0 = 0, cum1 = 0;
    if (w < NWORD) {
        for (int sg = 0; sg < SEG; ++sg) {
            size_t idx = (size_t)sg * NWORD + w;
            unsigned h = segHist[idx];
            segHist[idx] = ((unsigned)cum1 << 16) | (unsigned)cum0;  // offset-before
            cum0 += (int)(h & 0xffffu);
            cum1 += (int)(h >> 16);
        }
    }
    int deg0 = cum0, deg1 = cum1;
    int pair = deg0 + deg1;
    s[t] = pair; __syncthreads();
    for (int d = 1; d < 256; d <<= 1) {
        int x = (t >= d) ? s[t - d] : 0;
        __syncthreads();
        s[t] += x;
        __syncthreads();
    }
    int basep = s[t] - pair;   // exclusive prefix within block
    if (w < NWORD) {
        rowPtr[2 * w]     = basep;
        rowPtr[2 * w + 1] = basep + deg0;
        dinv[2 * w]     = 1.0f / (1.0f + (float)deg0);
        dinv[2 * w + 1] = 1.0f / (1.0f + (float)deg1);
    }
    if (t == 255) blkTot[blockIdx.x] = s[255];
}

// scan3 (scan2 folded in): every block wave-reduces its needed prefix of blkTot.
// Block b covers nodes [b*256, b*256+256) -> all share m = b>>1 (512 nodes/scanseg block).

__global__ void k_scan3(const int* __restrict__ blkTot, int* __restrict__ rowPtr) {
    int t = threadIdx.x;
    int b = blockIdx.x;
    int m = b >> 1;              // prefix length needed (0..97)
    int lane = t & 63;
    int v = 0;
    if (lane < m) v = blkTot[lane];
    if (lane + 64 < m) v += blkTot[lane + 64];
#pragma unroll
    for (int d = 1; d < 64; d <<= 1) v += __shfl_xor(v, d);
    int gid = b * 256 + t;
    if (gid < N_NODES) rowPtr[gid] += v;
    if (gid == 0) rowPtr[N_NODES] = N_EDGES;
}

// ---------------- bf16 MFMA GEMM (reg double-buffered) + fused CSR-fill ----------------
// tile 128x128, BK=32, 4 waves (2x2).
// EPI=0 (GEMM1): bf16 split write + fp8 byte store to Cq for gn<nsplit.
// EPI=1 (GEMM0): Hs (bf16 perm), Hq (fp8 perm), HmP (bf16 perm).

#define BKP 40   // 32 + 8 pad

template<int EPI>
__global__ __launch_bounds__(256) void k_gemm_fill(
        const unsigned short* __restrict__ A, const unsigned short* __restrict__ Bt,
        unsigned short* __restrict__ C0, int ld0,
        unsigned short* __restrict__ C1, int ld1, int nsplit,
        unsigned char* __restrict__ Cq,
        unsigned short* __restrict__ Hs, unsigned char* __restrict__ Hq,
        unsigned short* __restrict__ HmP,
        int M, int N, int K, int nxt,
        const unsigned* __restrict__ rc, const unsigned short* __restrict__ rank,
        const int* __restrict__ rowPtr, const unsigned short* __restrict__ segOff,
        unsigned short* __restrict__ colIdx) {
    __shared__ unsigned short As[128 * BKP];
    __shared__ unsigned short Bs[128 * BKP];
    int tid  = threadIdx.x;

    if ((int)blockIdx.x >= nxt) {
        int fid = (blockIdx.x - nxt) * gridDim.y + blockIdx.y;
        int e = fid * 256 + tid;
        if (e < N_EDGES) {
            unsigned x = rc[e];
            int r = (int)(x >> 16);
            int seg = e / EPB;
            int pos = rowPtr[r] + (int)segOff[(size_t)seg * N_NODES + r] + (int)rank[e];
            colIdx[pos] = (unsigned short)(x & 0xffffu);
        }
        return;
    }

    int lane = tid & 63, wid = tid >> 6;
    int wr = wid >> 1, wc = wid & 1;
    int bm = blockIdx.y * 128, bn = blockIdx.x * 128;

    int srow = tid >> 1;
    int scol = (tid & 1) * 16;

    int garow = min(bm + srow, M - 1);
    int gbrow = min(bn + srow, N - 1);

    f32x4 acc[4][4];
#pragma unroll
    for (int m = 0; m < 4; ++m)
#pragma unroll
        for (int n = 0; n < 4; ++n)
            acc[m][n] = (f32x4)(0.0f);

    int kg = (lane >> 4) * 8;
    int rA = wr * 64 + (lane & 15);
    int rB = wc * 64 + (lane & 15);

    const unsigned short* srcA = A + (size_t)garow * K + scol;
    const unsigned short* srcB = Bt + (size_t)gbrow * K + scol;
    ushort8 ra0 = *(const ushort8*)(srcA);
    ushort8 ra1 = *(const ushort8*)(srcA + 8);
    ushort8 rb0 = *(const ushort8*)(srcB);
    ushort8 rb1 = *(const ushort8*)(srcB + 8);

    for (int k0 = 0; k0 < K; k0 += 32) {
        *(ushort8*)&As[srow * BKP + scol]     = ra0;
        *(ushort8*)&As[srow * BKP + scol + 8] = ra1;
        *(ushort8*)&Bs[srow * BKP + scol]     = rb0;
        *(ushort8*)&Bs[srow * BKP + scol + 8] = rb1;
        __syncthreads();
        if (k0 + 32 < K) {   // prefetch next K-tile; flies during ds_read+MFMA
            ra0 = *(const ushort8*)(srcA + k0 + 32);
            ra1 = *(const ushort8*)(srcA + k0 + 40);
            rb0 = *(const ushort8*)(srcB + k0 + 32);
            rb1 = *(const ushort8*)(srcB + k0 + 40);
        }

        bf16x8 a[4], b[4];
#pragma unroll
        for (int m = 0; m < 4; ++m)
            a[m] = __builtin_bit_cast(bf16x8, *(const ushort8*)&As[(rA + m * 16) * BKP + kg]);
#pragma unroll
        for (int n = 0; n < 4; ++n)
            b[n] = __builtin_bit_cast(bf16x8, *(const ushort8*)&Bs[(rB + n * 16) * BKP + kg]);
#pragma unroll
        for (int m = 0; m < 4; ++m)
#pragma unroll
            for (int n = 0; n < 4; ++n)
                acc[m][n] = __builtin_amdgcn_mfma_f32_16x16x32_bf16(a[m], b[n], acc[m][n], 0, 0, 0);
        __syncthreads();
    }

    int col  = lane & 15;
    int rsub = (lane >> 4) * 4;

    if (EPI == 0) {
#pragma unroll
        for (int m = 0; m < 4; ++m) {
            int gm0 = bm + wr * 64 + m * 16 + rsub;
#pragma unroll
            for (int n = 0; n < 4; ++n) {
                int gn = bn + wc * 64 + n * 16 + col;
                if (gn >= N) continue;
#pragma unroll
                for (int j = 0; j < 4; ++j) {
                    int gm = gm0 + j;
                    if (gm >= M) continue;
                    float v = acc[m][n][j];
                    unsigned short b = f2bf(v);
                    if (gn < nsplit) {
                        C0[(size_t)gm * ld0 + gn] = b;
                        int pk = __builtin_amdgcn_cvt_pk_fp8_f32(v, v, 0, false);
                        Cq[(size_t)gm * nsplit + gn] = (unsigned char)(pk & 0xff);
                    } else {
                        C1[(size_t)gm * ld1 + (gn - nsplit)] = b;
                    }
                }
            }
        }
    } else {
        // permuted writes; this thread covers pos base = bn + wc*64 + col*4
#pragma unroll
        for (int m = 0; m < 4; ++m) {
            int gm0 = bm + wr * 64 + m * 16 + rsub;
#pragma unroll
            for (int j = 0; j < 4; ++j) {
                int gm = gm0 + j;
                if (gm >= M) continue;
                float v0 = acc[m][0][j], v1 = acc[m][1][j];
                float v2 = acc[m][2][j], v3 = acc[m][3][j];
                ushort4v o;
                o[0] = f2bf(v0); o[1] = f2bf(v1); o[2] = f2bf(v2); o[3] = f2bf(v3);
                if (bn < 256) {
                    int pos = bn + wc * 64 + col * 4;
                    *(ushort4v*)&Hs[(size_t)gm * 256 + pos] = o;
                    int pk = 0;
                    pk = __builtin_amdgcn_cvt_pk_fp8_f32(v0, v1, pk, false);
                    pk = __builtin_amdgcn_cvt_pk_fp8_f32(v2, v3, pk, true);
                    *(unsigned*)&Hq[(size_t)gm * 256 + pos] = (unsigned)pk;
                } else {
                    int pos = wc * 64 + col * 4;
                    *(ushort4v*)&HmP[(size_t)gm * 128 + pos] = o;
                }
            }
        }
    }
}

// ---------------- layer 0: wave-per-node, shfl-decoupled fp8 gather + ACM epilogue ----------------
// Hq fp8 perm [256 B/row]; Hs bf16 perm [256]; HmP bf16 perm [128].
// Packed f32x2 accumulators (v_pk_add_f32).

__global__ __launch_bounds__(256) void k_layer0(
        const unsigned short* __restrict__ Hs, const unsigned char* __restrict__ Hq,
        const unsigned short* __restrict__ HmP,
        const int* __restrict__ rowPtr, const unsigned short* __restrict__ colIdx,
        const float* __restrict__ dinv,
        const float* __restrict__ al, const float* __restrict__ ah,
        const float* __restrict__ am, const float* __restrict__ att,
        unsigned short* __restrict__ hout) {
    int lane = threadIdx.x & 63;
    int i = blockIdx.x * 4 + (threadIdx.x >> 6);

    int p0 = rfl(rowPtr[i]);
    int p1 = rfl(rowPtr[i + 1]);
    int deg = p1 - p0;
    f32x2 A01 = {0.f, 0.f}, A23 = {0.f, 0.f};
    int off4 = lane * 4;

    auto gath = [&](int js) -> unsigned {
        return *(const unsigned*)(Hq + ((size_t)(unsigned)js << 8) + off4);
    };
    auto addw = [&](unsigned w) {
        A01 += __builtin_amdgcn_cvt_pk_f32_fp8((int)w, false);
        A23 += __builtin_amdgcn_cvt_pk_f32_fp8((int)w, true);
    };

    for (int c = 0; c < deg; c += 64) {
        int rem = deg - c; if (rem > 64) rem = 64;
        int mycol = (int)colIdx[p0 + c + (lane < rem ? lane : 0)];
        int q = 0;
        for (; q + 7 < rem; q += 8) {
            int j0 = rfl(__shfl(mycol, q + 0));
            int j1 = rfl(__shfl(mycol, q + 1));
            int j2 = rfl(__shfl(mycol, q + 2));
            int j3 = rfl(__shfl(mycol, q + 3));
            int j4 = rfl(__shfl(mycol, q + 4));
            int j5 = rfl(__shfl(mycol, q + 5));
            int j6 = rfl(__shfl(mycol, q + 6));
            int j7 = rfl(__shfl(mycol, q + 7));
            unsigned w0 = gath(j0), w1 = gath(j1), w2 = gath(j2), w3 = gath(j3);
            unsigned w4 = gath(j4), w5 = gath(j5), w6 = gath(j6), w7 = gath(j7);
            addw(w0); addw(w1); addw(w2); addw(w3);
            addw(w4); addw(w5); addw(w6); addw(w7);
        }
        for (; q < rem; ++q) {
            int j = rfl(__shfl(mycol, q));
            addw(gath(j));
        }
    }
    float a0 = A01.x, a1 = A01.y, a2 = A23.x, a3 = A23.y;

    uint2 sv = *(const uint2*)(Hs + (size_t)i * 256 + off4);   // 4 bf16 self vals
    float s0 = bflo(sv.x), s1 = bfhi(sv.x), s2 = bflo(sv.y), s3 = bfhi(sv.y);
    float di = dinv[i];
    float l0 = di * (s0 + a0), l1 = di * (s1 + a1);
    float l2 = di * (s2 + a2), l3 = di * (s3 + a3);

    float ol0 = fmaxf(l0, 0.f), ol1 = fmaxf(l1, 0.f);
    float ol2 = fmaxf(l2, 0.f), ol3 = fmaxf(l3, 0.f);
    float oh0 = fmaxf(s0 - l0, 0.f), oh1 = fmaxf(s1 - l1, 0.f);
    float oh2 = fmaxf(s2 - l2, 0.f), oh3 = fmaxf(s3 - l3, 0.f);

    int c0 = ((lane >> 4) << 6) + (lane & 15);   // true feat of q=0

    float om0 = 0.f, om1 = 0.f, om2 = 0.f, om3 = 0.f;
    float prA, prM = 0.f;
    if (lane < 32) {
        uint2 hv = *(const uint2*)(HmP + (size_t)i * 128 + off4);
        om0 = fmaxf(bflo(hv.x), 0.f); om1 = fmaxf(bfhi(hv.x), 0.f);
        om2 = fmaxf(bflo(hv.y), 0.f); om3 = fmaxf(bfhi(hv.y), 0.f);
        prA = ol0 * al[c0] + ol1 * al[c0 + 16] + ol2 * al[c0 + 32] + ol3 * al[c0 + 48];
        prM = om0 * am[c0] + om1 * am[c0 + 16] + om2 * am[c0 + 32] + om3 * am[c0 + 48];
    } else {
        int ch = c0 - 128;
        prA = oh0 * ah[ch] + oh1 * ah[ch + 16] + oh2 * ah[ch + 32] + oh3 * ah[ch + 48];
    }

#pragma unroll
    for (int d = 1; d < 32; d <<= 1) prA += __shfl_xor(prA, d);
#pragma unroll
    for (int d = 1; d < 32; d <<= 1) prM += __shfl_xor(prM, d);
    float g0 = __shfl(prA, 0);
    float g1 = __shfl(prA, 32);
    float g2 = __shfl(prM, 0);

    float sg0 = sigmoidf_(g0), sg1 = sigmoidf_(g1), sg2 = sigmoidf_(g2);
    const float inv3 = (1.0f / 3.0f);
    float e0 = (sg0 * att[0] + sg1 * att[3] + sg2 * att[6]) * inv3;
    float e1 = (sg0 * att[1] + sg1 * att[4] + sg2 * att[7]) * inv3;
    float e2 = (sg0 * att[2] + sg1 * att[5] + sg2 * att[8]) * inv3;
    float mx = fmaxf(e0, fmaxf(e1, e2));
    float x0 = expf(e0 - mx), x1 = expf(e1 - mx), x2 = expf(e2 - mx);
    float inv = 1.0f / (x0 + x1 + x2);
    float c0f = 3.0f * inv * x0, c1f = 3.0f * inv * x1, c2f = 3.0f * inv * x2;

    int src = lane | 32;
    float th0 = __shfl(oh0, src), th1 = __shfl(oh1, src);
    float th2 = __shfl(oh2, src), th3 = __shfl(oh3, src);

    if (lane < 32) {
        // hbuf permuted: pos p = lane*4+q -> true feat c_q (matches W1t k-perm)
        ushort4v o;
        o[0] = f2bf(c0f * ol0 + c1f * th0 + c2f * om0);
        o[1] = f2bf(c0f * ol1 + c1f * th1 + c2f * om1);
        o[2] = f2bf(c0f * ol2 + c1f * th2 + c2f * om2);
        o[3] = f2bf(c0f * ol3 + c1f * th3 + c2f * om3);
        *(ushort4v*)&hout[(size_t)i * 128 + off4] = o;
    }
}

// ---------------- layer 1: wave-per-node, shfl-decoupled fp8 gather + ACM epilogue ----------------
// H1q fp8 plain [80 B/row]; H1g bf16 plain [80] (self); H1m bf16 [40].

__global__ __launch_bounds__(256) void k_layer1(
        const unsigned short* __restrict__ H1g, const unsigned char* __restrict__ H1q,
        const unsigned short* __restrict__ H1m,
        const int* __restrict__ rowPtr, const unsigned short* __restrict__ colIdx,
        const float* __restrict__ dinv,
        const float* __restrict__ al, const float* __restrict__ ah,
        const float* __restrict__ am, const float* __restrict__ att,
        float* __restrict__ out) {
    int lane = threadIdx.x & 63;
    int i = blockIdx.x * 4 + (threadIdx.x >> 6);

    int p0 = rfl(rowPtr[i]);
    int p1 = rfl(rowPtr[i + 1]);
    int deg = p1 - p0;
    f32x2 A01 = {0.f, 0.f}, A23 = {0.f, 0.f};
    bool active = lane < 20;
    int off4 = lane * 4;
    int offc = active ? off4 : 0;    // clamp: inactive lanes load safely in-row

    auto gath = [&](int js) -> unsigned {
        return *(const unsigned*)(H1q + (size_t)((unsigned)js * 80u) + offc);
    };
    auto addw = [&](unsigned w) {
        A01 += __builtin_amdgcn_cvt_pk_f32_fp8((int)w, false);
        A23 += __builtin_amdgcn_cvt_pk_f32_fp8((int)w, true);
    };

    for (int c = 0; c < deg; c += 64) {
        int rem = deg - c; if (rem > 64) rem = 64;
        int mycol = (int)colIdx[p0 + c + (lane < rem ? lane : 0)];
        int q = 0;
        for (; q + 7 < rem; q += 8) {
            int j0 = rfl(__shfl(mycol, q + 0));
            int j1 = rfl(__shfl(mycol, q + 1));
            int j2 = rfl(__shfl(mycol, q + 2));
            int j3 = rfl(__shfl(mycol, q + 3));
            int j4 = rfl(__shfl(mycol, q + 4));
            int j5 = rfl(__shfl(mycol, q + 5));
            int j6 = rfl(__shfl(mycol, q + 6));
            int j7 = rfl(__shfl(mycol, q + 7));
            unsigned w0 = gath(j0), w1 = gath(j1), w2 = gath(j2), w3 = gath(j3);
            unsigned w4 = gath(j4), w5 = gath(j5), w6 = gath(j6), w7 = gath(j7);
            addw(w0); addw(w1); addw(w2); addw(w3);
            addw(w4); addw(w5); addw(w6); addw(w7);
        }
        for (; q < rem; ++q) {
            int j = rfl(__shfl(mycol, q));
            addw(gath(j));
        }
    }
    float a0 = A01.x, a1 = A01.y, a2 = A23.x, a3 = A23.y;

    float s0 = 0.f, s1 = 0.f, s2 = 0.f, s3 = 0.f;
    if (active) {
        uint2 sv = *(const uint2*)(H1g + (size_t)i * 80 + off4);  // 4 bf16 self
        s0 = bflo(sv.x); s1 = bfhi(sv.x); s2 = bflo(sv.y); s3 = bfhi(sv.y);
    }
    float di = dinv[i];
    float l0 = di * (s0 + a0), l1 = di * (s1 + a1);
    float l2 = di * (s2 + a2), l3 = di * (s3 + a3);

    float ol0 = fmaxf(l0, 0.f), ol1 = fmaxf(l1, 0.f);
    float ol2 = fmaxf(l2, 0.f), ol3 = fmaxf(l3, 0.f);
    float oh0 = fmaxf(s0 - l0, 0.f), oh1 = fmaxf(s1 - l1, 0.f);
    float oh2 = fmaxf(s2 - l2, 0.f), oh3 = fmaxf(s3 - l3, 0.f);

    float om0 = 0.f, om1 = 0.f, om2 = 0.f, om3 = 0.f;
    float r0 = 0.f, r1 = 0.f, r2 = 0.f;
    if (lane < 10) {
        uint2 hv = *(const uint2*)(H1m + (size_t)i * 40 + off4);
        om0 = fmaxf(bflo(hv.x), 0.f); om1 = fmaxf(bfhi(hv.x), 0.f);
        om2 = fmaxf(bflo(hv.y), 0.f); om3 = fmaxf(bfhi(hv.y), 0.f);
        float4 alv = *(const float4*)(al + off4);
        float4 amv = *(const float4*)(am + off4);
        r0 = ol0 * alv.x + ol1 * alv.y + ol2 * alv.z + ol3 * alv.w;
        r2 = om0 * amv.x + om1 * amv.y + om2 * amv.z + om3 * amv.w;
    } else if (lane < 20) {
        float4 ahv = *(const float4*)(ah + (off4 - 40));
        r1 = oh0 * ahv.x + oh1 * ahv.y + oh2 * ahv.z + oh3 * ahv.w;
    }

#pragma unroll
    for (int d = 1; d < 64; d <<= 1) r0 += __shfl_xor(r0, d);
#pragma unroll
    for (int d = 1; d < 64; d <<= 1) r1 += __shfl_xor(r1, d);
#pragma unroll
    for (int d = 1; d < 64; d <<= 1) r2 += __shfl_xor(r2, d);

    float sg0 = sigmoidf_(r0), sg1 = sigmoidf_(r1), sg2 = sigmoidf_(r2);
    const float inv3 = (1.0f / 3.0f);
    float e0 = (sg0 * att[0] + sg1 * att[3] + sg2 * att[6]) * inv3;
    float e1 = (sg0 * att[1] + sg1 * att[4] + sg2 * att[7]) * inv3;
    float e2 = (sg0 * att[2] + sg1 * att[5] + sg2 * att[8]) * inv3;
    float mx = fmaxf(e0, fmaxf(e1, e2));
    float x0 = expf(e0 - mx), x1 = expf(e1 - mx), x2 = expf(e2 - mx);
    float inv = 1.0f / (x0 + x1 + x2);
    float c0 = 3.0f * inv * x0, c1 = 3.0f * inv * x1, c2 = 3.0f * inv * x2;

    // oh for output feat f (=4l+k) lives on lane l+10, same k
    int src = (lane + 10) & 63;
    float th0 = __shfl(oh0, src), th1 = __shfl(oh1, src);
    float th2 = __shfl(oh2, src), th3 = __shfl(oh3, src);

    if (lane < 10) {
        float4 o;
        o.x = c0 * ol0 + c1 * th0 + c2 * om0;
        o.y = c0 * ol1 + c1 * th1 + c2 * om1;
        o.z = c0 * ol2 + c1 * th2 + c2 * om2;
        o.w = c0 * ol3 + c1 * th3 + c2 * om3;
        *(float4*)&out[(size_t)i * 40 + off4] = o;
    }
}

// ---------------- launch ----------------

extern "C" void kernel_launch(void* const* d_in, const int* in_sizes, int n_in,
                              void* d_out, int out_size, void* d_ws, size_t ws_size,
                              hipStream_t stream) {
    const float* x    = (const float*)d_in[0];
    const int*   ei   = (const int*)d_in[1];
    const float* Wl0  = (const float*)d_in[2];
    const float* Wh0  = (const float*)d_in[3];
    const float* Wm0  = (const float*)d_in[4];
    const float* al0  = (const float*)d_in[5];
    const float* ah0  = (const float*)d_in[6];
    const float* am0  = (const float*)d_in[7];
    const float* att0 = (const float*)d_in[8];
    const float* Wl1  = (const float*)d_in[9];
    const float* Wh1  = (const float*)d_in[10];
    const float* Wm1  = (const float*)d_in[11];
    const float* al1  = (const float*)d_in[12];
    const float* ah1  = (const float*)d_in[13];
    const float* am1  = (const float*)d_in[14];
    const float* att1 = (const float*)d_in[15];
    float* out = (float*)d_out;

    char* ws = (char*)d_ws;
    size_t off = 0;
    auto alloc = [&](size_t bytes) -> char* {
        char* p = ws + off;
        off += (bytes + 255) & ~(size_t)255;
        return p;
    };
    int*      rowPtr  = (int*)     alloc((size_t)(N_NODES + 1) * 4);
    int*      blkTot  = (int*)     alloc(256 * 4);
    unsigned* segHist = (unsigned*)alloc((size_t)SEG * NWORD * 4);   // 12.8 MB
    unsigned short* rank   = (unsigned short*)alloc((size_t)N_EDGES * 2);
    unsigned*       rc     = (unsigned*)      alloc((size_t)N_EDGES * 4);
    unsigned short* colIdx = (unsigned short*)alloc((size_t)N_EDGES * 2 + 256);
    float* dinv   = (float*)alloc((size_t)N_NODES * 4);
    unsigned short* W0t  = (unsigned short*)alloc((size_t)W0N * IN_F * 2);
    unsigned short* W1t  = (unsigned short*)alloc((size_t)W1N * HID_F * 2);
    unsigned short* xb   = (unsigned short*)alloc((size_t)N_NODES * IN_F * 2);
    unsigned short* Hs   = (unsigned short*)alloc((size_t)N_NODES * 256 * 2);
    unsigned char*  Hq   = (unsigned char*) alloc((size_t)N_NODES * 256);
    unsigned short* HmP  = (unsigned short*)alloc((size_t)N_NODES * 128 * 2);
    unsigned short* H1g  = (unsigned short*)alloc((size_t)N_NODES * 80 * 2);
    unsigned char*  H1q  = (unsigned char*) alloc((size_t)N_NODES * 80 + 256);  // +pad
    unsigned short* H1m  = (unsigned short*)alloc((size_t)N_NODES * 40 * 2);
    unsigned short* hbuf = (unsigned short*)alloc((size_t)N_NODES * HID_F * 2);

    // 1. fused: segmented LDS histogram | x->bf16 | W packs
    k_hp<<<HPREPB, 256, 0, stream>>>(ei, segHist, rank, rc,
                                     x, xb, Wl0, Wh0, Wm0, W0t,
                                     Wl1, Wh1, Wm1, W1t);
    // 2. segment-offset scan + local rowPtr + dinv
    k_scanseg<<<WB, 256, 0, stream>>>(segHist, rowPtr, dinv, blkTot);
    // 3. apply block offsets (scan2 folded in)
    k_scan3<<<NB, 256, 0, stream>>>(blkTot, rowPtr);
    // 4. GEMM0 (layer-0 epilogue: Hs/Hq/HmP) with fused atomic-free CSR fill
    {
        dim3 grid(3 + 8, (N_NODES + 127) / 128);
        k_gemm_fill<1><<<grid, 256, 0, stream>>>(xb, W0t,
                                                 nullptr, 0, nullptr, 0, 0, nullptr,
                                                 Hs, Hq, HmP,
                                                 N_NODES, W0N, IN_F, 3,
                                                 rc, rank, rowPtr,
                                                 (const unsigned short*)segHist, colIdx);
    }
    // 5. layer-0 aggregate + epilogue
    k_layer0<<<N_NODES / 4, 256, 0, stream>>>(Hs, Hq, HmP, rowPtr, colIdx, dinv,
                                              al0, ah0, am0, att0, hbuf);
    // 6. GEMM1 (bf16 H1g/H1m + fp8 H1q)
    {
        dim3 grid(1, (N_NODES + 127) / 128);
        k_gemm_fill<0><<<grid, 256, 0, stream>>>(hbuf, W1t,
                                                 H1g, 80, H1m, 40, 80, H1q,
                                                 nullptr, nullptr, nullptr,
                                                 N_NODES, W1N, HID_F, 1,
                                                 nullptr, nullptr, nullptr, nullptr, nullptr);
    }
    // 7. layer-1 aggregate + epilogue
    k_layer1<<<N_NODES / 4, 256, 0, stream>>>(H1g, H1q, H1m, rowPtr, colIdx, dinv,
                                              al1, ah1, am1, att1, out);
}